// Round 5
// baseline (714.855 us; speedup 1.0000x reference)
//
#include <hip/hip_runtime.h>
#include <hip/hip_bf16.h>
#include <math.h>

#define DEMB 64
#define M_NODES 4
#define NPB 128            // nodes per bucket
#define BCH 8              // chunks (≈ XCDs)
#define SENT_CAP 4096      // LDS staging entries per bucket

// ---------------- helpers ----------------

__device__ __forceinline__ float bf2f(unsigned short u) {
    union { unsigned int i; float f; } c; c.i = ((unsigned int)u) << 16; return c.f;
}
__device__ __forceinline__ unsigned short f2bf(float f) {
    union { float f; unsigned int i; } c; c.f = f;
    unsigned int r = c.i + 0x7FFFu + ((c.i >> 16) & 1u);   // RNE
    return (unsigned short)(r >> 16);
}
__device__ __forceinline__ float rdlane(float v, int k) {
    return __int_as_float(__builtin_amdgcn_readlane(__float_as_int(v), k));
}

// ---------------- preprocessing: bucketed CSR build ----------------

__global__ void initcells_kernel(int* __restrict__ cellcnt, int NC) {
    int i = blockIdx.x * blockDim.x + threadIdx.x;
    if (i < NC) cellcnt[i] = 0;
}

// histogram: edges -> (bucket, chunk) cell counts
__global__ void hist_kernel(const int* __restrict__ ei, int* __restrict__ cellcnt, int E) {
    int e = blockIdx.x * blockDim.x + threadIdx.x;
    if (e >= E) return;
    int c = ei[E + e];
    int cell = (c >> 7) * BCH + (blockIdx.x & (BCH - 1));
    atomicAdd(&cellcnt[cell], 1);
}

// single-block scan of cell counts -> cellbase (exclusive, +sentinel), zero cellfill
__global__ void scan_cells_kernel(const int* __restrict__ cellcnt, int* __restrict__ cellbase,
                                  int* __restrict__ cellfill, int NC) {
    __shared__ int sh[1024];
    int t = threadIdx.x;
    int chunk = (NC + 1023) >> 10;
    int lo = t * chunk;
    int hi = lo + chunk; if (hi > NC) hi = NC;
    int s = 0;
    for (int i = lo; i < hi; i++) s += cellcnt[i];
    sh[t] = s;
    __syncthreads();
    for (int off = 1; off < 1024; off <<= 1) {
        int v = (t >= off) ? sh[t - off] : 0;
        __syncthreads();
        sh[t] += v;
        __syncthreads();
    }
    int run = sh[t] - s;
    for (int i = lo; i < hi; i++) { cellbase[i] = run; cellfill[i] = 0; run += cellcnt[i]; }
    if (t == 1023) cellbase[NC] = sh[1023];   // total = E
}

// bin: append packed entries (ldest<<25 | src, ew) to cells; UNSIGNED packing.
__global__ void bin_kernel(const int* __restrict__ ei, const float* __restrict__ ew,
                           const int* __restrict__ cellbase, int* __restrict__ cellfill,
                           int2* __restrict__ cells, int E) {
    int e = blockIdx.x * blockDim.x + threadIdx.x;
    if (e >= E) return;
    unsigned int r = (unsigned int)ei[e];
    int c = ei[E + e];
    int cell = (c >> 7) * BCH + (blockIdx.x & (BCH - 1));
    int pos = cellbase[cell] + atomicAdd(&cellfill[cell], 1);
    int2 ent;
    ent.x = (int)((((unsigned int)(c & 127)) << 25) | r);
    ent.y = __float_as_int(ew[e]);
    cells[pos] = ent;
}

// bucket pass: per 128-node bucket, count deg/cnt in LDS, local scan (padded to even),
// write dis + rowse, sort entries into LDS, stream CSR segment out coalesced.
__global__ __launch_bounds__(256) void bucket_kernel(
    const int2* __restrict__ cells, const int* __restrict__ cellbase,
    int2* __restrict__ csr, int2* __restrict__ rowse, float* __restrict__ dis, int N) {
    __shared__ float sdeg[NPB];
    __shared__ int scnt[NPB];
    __shared__ int sstart[NPB];
    __shared__ int sfill[NPB];
    __shared__ int stotal;
    __shared__ int2 sent[SENT_CAP];

    int b = blockIdx.x;
    int t = threadIdx.x;
    int nodebase = b * NPB;
    int nNodes = N - nodebase; if (nNodes > NPB) nNodes = NPB;

    if (t < NPB) { sdeg[t] = 1.0f; scnt[t] = 0; sfill[t] = 0; }
    __syncthreads();

    int lo = cellbase[b * BCH];
    int hi = cellbase[(b + 1) * BCH];   // contiguous (bucket-major cell layout)
    int nent = hi - lo;

    // pass 1: per-node count + weighted degree (UNSIGNED decode of ld)
    for (int i = lo + t; i < hi; i += 256) {
        int2 en = cells[i];
        unsigned int ld = ((unsigned int)en.x) >> 25;    // in [0, 128)
        atomicAdd(&scnt[ld], 1);
        atomicAdd(&sdeg[ld], __int_as_float(en.y));
    }
    __syncthreads();

    // serial local scan of even-padded counts
    if (t == 0) {
        int run = 0;
        for (int n = 0; n < nNodes; n++) {
            sstart[n] = run;
            run += (scnt[n] + 1) & ~1;
        }
        stotal = run;
    }
    __syncthreads();

    int gbase = lo + b * NPB;   // slack of NPB entries per bucket covers padding
    if (t < nNodes) {
        int node = nodebase + t;
        dis[node] = rsqrtf(sdeg[t]);
        int gs = gbase + sstart[t];
        rowse[node] = make_int2(gs, gs + ((scnt[t] + 1) & ~1));
    }

    if (nent + nNodes <= SENT_CAP) {
        // pass 2: scatter into LDS, then coalesced stream-out
        for (int i = lo + t; i < hi; i += 256) {
            int2 en = cells[i];
            unsigned int ld = ((unsigned int)en.x) >> 25;
            int pos = sstart[ld] + atomicAdd(&sfill[ld], 1);
            sent[pos] = make_int2(en.x & 0x1FFFFFF, en.y);
        }
        __syncthreads();
        if (t < nNodes && (scnt[t] & 1))
            sent[sstart[t] + scnt[t]] = make_int2(nodebase + t, 0);   // dummy, w=0
        __syncthreads();
        int tot = stotal;
        for (int i = t; i < tot; i += 256)
            csr[gbase + i] = sent[i];
    } else {
        // fallback: direct global scatter (correctness path)
        for (int i = lo + t; i < hi; i += 256) {
            int2 en = cells[i];
            unsigned int ld = ((unsigned int)en.x) >> 25;
            int pos = atomicAdd(&sfill[ld], 1);
            csr[gbase + sstart[ld] + pos] = make_int2(en.x & 0x1FFFFFF, en.y);
        }
        __syncthreads();
        if (t < nNodes && (scnt[t] & 1))
            csr[gbase + sstart[t] + scnt[t]] = make_int2(nodebase + t, 0);
    }
}

// ---------------- encoder: stores s = dis * h_enc ----------------

__global__ __launch_bounds__(256, 4) void encoder_kernel(
    const float* __restrict__ x, const float* __restrict__ dis,
    const float* __restrict__ w1, const float* __restrict__ b1,
    const float* __restrict__ w2, const float* __restrict__ b2,
    unsigned short* __restrict__ hout, int N) {
    int lane = threadIdx.x & 63;
    int wid = __builtin_amdgcn_readfirstlane((blockIdx.x * blockDim.x + threadIdx.x) >> 6);
    int n0 = wid * M_NODES;
    if (n0 >= N) return;

    float w2col[DEMB];
    #pragma unroll
    for (int k = 0; k < DEMB; k++) w2col[k] = w2[k * DEMB + lane];
    float w1a = w1[lane], w1b = w1[DEMB + lane];
    float b1v = b1[lane], b2v = b2[lane];

    float xv = 0.0f;
    if (lane < 2 * M_NODES && n0 * 2 + lane < 2 * N) xv = x[n0 * 2 + lane];

    #pragma unroll
    for (int m = 0; m < M_NODES; m++) {
        int node = n0 + m;
        if (node >= N) continue;
        float x0 = rdlane(xv, 2 * m);
        float x1 = rdlane(xv, 2 * m + 1);
        float t = fmaxf(0.0f, fmaf(x0, w1a, fmaf(x1, w1b, b1v)));
        float y = b2v;
        #pragma unroll
        for (int k = 0; k < DEMB; k++)
            y = fmaf(rdlane(t, k), w2col[k], y);
        hout[(size_t)node * DEMB + lane] = f2bf(y * dis[node]);  // scaled state
    }
}

// ------- fused layer, paired gathers: lane = (p=edge parity, q=feature pair) -------
// agg = dis_c*(Σ ew*s_src + s_c);  h_next = relu(agg·W + b);  store (scaleOut? dis_c:1)*h_next

__global__ __launch_bounds__(256, 4) void layer_kernel(
    const unsigned short* __restrict__ hin, const int2* __restrict__ csr,
    const int2* __restrict__ rowse, const float* __restrict__ dis,
    const float* __restrict__ W, const float* __restrict__ bias,
    unsigned short* __restrict__ hout, int N, int scaleOut) {
    int lane = threadIdx.x & 63;
    int wid = __builtin_amdgcn_readfirstlane((blockIdx.x * blockDim.x + threadIdx.x) >> 6);
    int n0 = wid * M_NODES;
    if (n0 >= N) return;

    const unsigned int* hin32 = (const unsigned int*)hin;   // 2 bf16 per dword
    int p = lane >> 5;        // which edge of the pair this half-wave handles
    int q = lane & 31;        // feature-pair index (features 2q, 2q+1)

    float Wcol[DEMB];
    #pragma unroll
    for (int k = 0; k < DEMB; k++) Wcol[k] = W[k * DEMB + lane];
    float bv = bias[lane];

    float2 acc[M_NODES];
    #pragma unroll
    for (int m = 0; m < M_NODES; m++) {
        int node = n0 + m;
        if (node >= N) { acc[m] = make_float2(0.0f, 0.0f); continue; }
        // self-loop term (only low half contributes; high half adds 0)
        unsigned int su = hin32[(size_t)node * 32 + q];
        float2 a;
        a.x = (p == 0) ? bf2f(su & 0xffff) : 0.0f;
        a.y = (p == 0) ? bf2f(su >> 16) : 0.0f;
        int2 se = rowse[node];
        int i = se.x, e = se.y;             // even-length rows (padded)
        for (; i + 8 <= e; i += 8) {
            int2 e0 = csr[i + p];
            int2 e1 = csr[i + 2 + p];
            int2 e2 = csr[i + 4 + p];
            int2 e3 = csr[i + 6 + p];
            unsigned int u0 = hin32[(size_t)e0.x * 32 + q];
            unsigned int u1 = hin32[(size_t)e1.x * 32 + q];
            unsigned int u2 = hin32[(size_t)e2.x * 32 + q];
            unsigned int u3 = hin32[(size_t)e3.x * 32 + q];
            float w0 = __int_as_float(e0.y), w1 = __int_as_float(e1.y);
            float w2 = __int_as_float(e2.y), w3 = __int_as_float(e3.y);
            a.x = fmaf(w0, bf2f(u0 & 0xffff), a.x); a.y = fmaf(w0, bf2f(u0 >> 16), a.y);
            a.x = fmaf(w1, bf2f(u1 & 0xffff), a.x); a.y = fmaf(w1, bf2f(u1 >> 16), a.y);
            a.x = fmaf(w2, bf2f(u2 & 0xffff), a.x); a.y = fmaf(w2, bf2f(u2 >> 16), a.y);
            a.x = fmaf(w3, bf2f(u3 & 0xffff), a.x); a.y = fmaf(w3, bf2f(u3 >> 16), a.y);
        }
        for (; i < e; i += 2) {
            int2 en = csr[i + p];
            unsigned int u = hin32[(size_t)en.x * 32 + q];
            float w = __int_as_float(en.y);
            a.x = fmaf(w, bf2f(u & 0xffff), a.x);
            a.y = fmaf(w, bf2f(u >> 16), a.y);
        }
        // combine the two half-wave partial sums
        a.x += __shfl_xor(a.x, 32);
        a.y += __shfl_xor(a.y, 32);
        acc[m] = a;
    }

    #pragma unroll
    for (int m = 0; m < M_NODES; m++) {
        int node = n0 + m;
        if (node >= N) continue;
        float d = dis[node];
        float dot = 0.0f;
        #pragma unroll
        for (int kk = 0; kk < 32; kk++) {
            dot = fmaf(rdlane(acc[m].x, kk), Wcol[2 * kk], dot);
            dot = fmaf(rdlane(acc[m].y, kk), Wcol[2 * kk + 1], dot);
        }
        float y = fmaxf(fmaf(d, dot, bv), 0.0f);
        float os = scaleOut ? d : 1.0f;
        hout[(size_t)node * DEMB + lane] = f2bf(y * os);
    }
}

// ---------------- decoder + softmax + residual ----------------

__global__ __launch_bounds__(256, 4) void decoder_kernel(
    const unsigned short* __restrict__ h, const float* __restrict__ x,
    const float* __restrict__ dw1, const float* __restrict__ db1,
    const float* __restrict__ dw2, const float* __restrict__ db2,
    float* __restrict__ out, int N) {
    int lane = threadIdx.x & 63;
    int wid = __builtin_amdgcn_readfirstlane((blockIdx.x * blockDim.x + threadIdx.x) >> 6);
    int n0 = wid * M_NODES;
    if (n0 >= N) return;

    float w1col[DEMB];
    #pragma unroll
    for (int k = 0; k < DEMB; k++) w1col[k] = dw1[k * DEMB + lane];
    float db1v = db1[lane];
    float w20 = dw2[lane * 2], w21 = dw2[lane * 2 + 1];
    float db20 = db2[0], db21 = db2[1];

    float xv = 0.0f;
    if (lane < 2 * M_NODES && n0 * 2 + lane < 2 * N) xv = x[n0 * 2 + lane];

    float myout = 0.0f;
    #pragma unroll
    for (int m = 0; m < M_NODES; m++) {
        int node = n0 + m;
        if (node >= N) continue;
        float hv = bf2f(h[(size_t)node * DEMB + lane]);
        float y = db1v;
        #pragma unroll
        for (int k = 0; k < DEMB; k++)
            y = fmaf(rdlane(hv, k), w1col[k], y);
        float d1 = fmaxf(y, 0.0f);
        float p0 = d1 * w20, p1 = d1 * w21;
        #pragma unroll
        for (int off = 32; off > 0; off >>= 1) {
            p0 += __shfl_xor(p0, off);
            p1 += __shfl_xor(p1, off);
        }
        float o0 = p0 + db20, o1 = p1 + db21;
        float mm = fmaxf(o0, o1);
        float e0 = __expf(o0 - mm), e1 = __expf(o1 - mm);
        float inv = 1.0f / (e0 + e1);
        float r0 = e0 * inv + 2.0f * rdlane(xv, 2 * m);   // wc = [2, 0]
        float r1 = e1 * inv;
        if (lane == 2 * m) myout = r0;
        if (lane == 2 * m + 1) myout = r1;
    }
    if (lane < 2 * M_NODES && n0 * 2 + lane < 2 * N)
        out[n0 * 2 + lane] = myout;
}

// ---------------- launch ----------------

extern "C" void kernel_launch(void* const* d_in, const int* in_sizes, int n_in,
                              void* d_out, int out_size, void* d_ws, size_t ws_size,
                              hipStream_t stream) {
    const float* x      = (const float*)d_in[0];
    const int*   ei     = (const int*)d_in[1];
    const float* ew     = (const float*)d_in[2];
    const float* enc_w1 = (const float*)d_in[3];
    const float* enc_b1 = (const float*)d_in[4];
    const float* enc_w2 = (const float*)d_in[5];
    const float* enc_b2 = (const float*)d_in[6];
    const float* gcn_w  = (const float*)d_in[7];
    const float* gcn_b  = (const float*)d_in[8];
    const float* dec_w1 = (const float*)d_in[9];
    const float* dec_b1 = (const float*)d_in[10];
    const float* dec_w2 = (const float*)d_in[11];
    const float* dec_b2 = (const float*)d_in[12];
    float* out = (float*)d_out;

    const int N = in_sizes[0] / 2;
    const int E = in_sizes[2];
    const int L = in_sizes[7] / (DEMB * DEMB);
    const int B = (N + NPB - 1) / NPB;        // buckets
    const int NC = B * BCH;                   // cells

    // workspace layout (256B aligned); cells aliases hB (dead until layer 1)
    char* ws = (char*)d_ws;
    size_t o = 0;
    auto alignup = [](size_t v) { return (v + 255) & ~(size_t)255; };
    unsigned short* hA = (unsigned short*)(ws + o); o = alignup(o + (size_t)N * DEMB * 2);
    size_t hb_bytes = (size_t)N * DEMB * 2;
    size_t cells_bytes = (size_t)E * 8;
    size_t un = hb_bytes > cells_bytes ? hb_bytes : cells_bytes;
    unsigned short* hB = (unsigned short*)(ws + o);
    int2* cells = (int2*)(ws + o); o = alignup(o + un);
    float* dis     = (float*)(ws + o); o = alignup(o + (size_t)N * 4);
    int2*  rowse   = (int2*)(ws + o);  o = alignup(o + (size_t)N * 8);
    int*   cellcnt = (int*)(ws + o);   o = alignup(o + (size_t)NC * 4);
    int*   cellbase= (int*)(ws + o);   o = alignup(o + (size_t)(NC + 1) * 4);
    int*   cellfill= (int*)(ws + o);   o = alignup(o + (size_t)NC * 4);
    int2*  csr     = (int2*)(ws + o);  o = alignup(o + ((size_t)E + (size_t)B * NPB) * 8);

    const int TB = 256;
    dim3 blk(TB);
    dim3 gE((E + TB - 1) / TB);
    int waves = (N + M_NODES - 1) / M_NODES;
    dim3 gWaveM((waves + 3) / 4);   // 4 waves per 256-thread block

    initcells_kernel<<<(NC + TB - 1) / TB, blk, 0, stream>>>(cellcnt, NC);
    hist_kernel<<<gE, blk, 0, stream>>>(ei, cellcnt, E);
    scan_cells_kernel<<<1, 1024, 0, stream>>>(cellcnt, cellbase, cellfill, NC);
    bin_kernel<<<gE, blk, 0, stream>>>(ei, ew, cellbase, cellfill, cells, E);
    bucket_kernel<<<B, blk, 0, stream>>>(cells, cellbase, csr, rowse, dis, N);

    encoder_kernel<<<gWaveM, blk, 0, stream>>>(x, dis, enc_w1, enc_b1, enc_w2, enc_b2, hA, N);

    unsigned short* hin = hA;
    unsigned short* hout = hB;
    for (int l = 0; l < L; l++) {
        layer_kernel<<<gWaveM, blk, 0, stream>>>(hin, csr, rowse, dis,
                                                 gcn_w + (size_t)l * DEMB * DEMB,
                                                 gcn_b + (size_t)l * DEMB, hout, N,
                                                 (l < L - 1) ? 1 : 0);
        unsigned short* t = hin; hin = hout; hout = t;
    }

    decoder_kernel<<<gWaveM, blk, 0, stream>>>(hin, x, dec_w1, dec_b1, dec_w2, dec_b2, out, N);
}

// Round 6
// 710.154 us; speedup vs baseline: 1.0066x; 1.0066x over previous
//
#include <hip/hip_runtime.h>
#include <hip/hip_bf16.h>
#include <math.h>

#define DEMB 64

// ---------------- helpers ----------------

__device__ __forceinline__ float bf2f(unsigned short u) {
    union { unsigned int i; float f; } c; c.i = ((unsigned int)u) << 16; return c.f;
}
__device__ __forceinline__ unsigned short f2bf(float f) {
    union { float f; unsigned int i; } c; c.f = f;
    unsigned int r = c.i + 0x7FFFu + ((c.i >> 16) & 1u);   // RNE
    return (unsigned short)(r >> 16);
}
__device__ __forceinline__ float rdlane(float v, int k) {
    return __int_as_float(__builtin_amdgcn_readlane(__float_as_int(v), k));
}

// ---------------- graph preprocessing ----------------

__global__ void init_cnt_kernel(int* __restrict__ cnt, int N) {
    int i = blockIdx.x * blockDim.x + threadIdx.x;
    if (i < N) cnt[i] = 0;
}

__global__ void hist_kernel(const int* __restrict__ ei, int* __restrict__ cnt, int E) {
    int e = blockIdx.x * blockDim.x + threadIdx.x;
    if (e >= E) return;
    atomicAdd(&cnt[ei[E + e]], 1);
}

// -------- 3-phase multi-block scan: cnt[N] -> rowptr[N+1] (exclusive) + rp2 copy --------
__global__ __launch_bounds__(256) void scan_sums_kernel(const int* __restrict__ cnt,
                                                        int* __restrict__ part, int N) {
    int b = blockIdx.x, t = threadIdx.x, lane = t & 63, w = t >> 6;
    int idx = b * 1024 + t * 4;
    int s = 0;
    if (idx + 3 < N) {
        int4 v = *(const int4*)(cnt + idx);
        s = v.x + v.y + v.z + v.w;
    } else {
        for (int j = 0; j < 4; j++) if (idx + j < N) s += cnt[idx + j];
    }
    #pragma unroll
    for (int off = 32; off > 0; off >>= 1) s += __shfl_down(s, off);
    __shared__ int wt[4];
    if (lane == 0) wt[w] = s;
    __syncthreads();
    if (t == 0) part[b] = wt[0] + wt[1] + wt[2] + wt[3];
}

__global__ void scan_offsets_kernel(int* __restrict__ part, int* __restrict__ rowptr,
                                    int NB, int N) {
    __shared__ int sh[1024];
    int t = threadIdx.x;
    int mine = (t < NB) ? part[t] : 0;
    sh[t] = mine;
    __syncthreads();
    for (int off = 1; off < 1024; off <<= 1) {
        int v = (t >= off) ? sh[t - off] : 0;
        __syncthreads();
        sh[t] += v;
        __syncthreads();
    }
    if (t < NB) part[t] = sh[t] - mine;   // exclusive
    if (t == 1023) rowptr[N] = sh[1023];  // total = E
}

__global__ __launch_bounds__(256) void scan_apply_kernel(const int* __restrict__ cnt,
                                                         const int* __restrict__ part,
                                                         int* __restrict__ rowptr,
                                                         int* __restrict__ rp2, int N) {
    int b = blockIdx.x, t = threadIdx.x, lane = t & 63, w = t >> 6;
    int idx = b * 1024 + t * 4;
    int v0 = 0, v1 = 0, v2 = 0, v3 = 0;
    if (idx + 3 < N) {
        int4 v = *(const int4*)(cnt + idx);
        v0 = v.x; v1 = v.y; v2 = v.z; v3 = v.w;
    } else {
        if (idx     < N) v0 = cnt[idx];
        if (idx + 1 < N) v1 = cnt[idx + 1];
        if (idx + 2 < N) v2 = cnt[idx + 2];
        if (idx + 3 < N) v3 = cnt[idx + 3];
    }
    int tsum = v0 + v1 + v2 + v3;
    int sc = tsum;
    #pragma unroll
    for (int off = 1; off < 64; off <<= 1) {
        int u = __shfl_up(sc, off);
        if (lane >= off) sc += u;
    }
    __shared__ int wt[4];
    if (lane == 63) wt[w] = sc;
    __syncthreads();
    int woff = 0;
    for (int i = 0; i < w; i++) woff += wt[i];
    int ex = part[b] + woff + sc - tsum;
    if (idx + 3 < N) {
        int4 o;
        o.x = ex; o.y = ex + v0; o.z = ex + v0 + v1; o.w = ex + v0 + v1 + v2;
        *(int4*)(rowptr + idx) = o;
        *(int4*)(rp2 + idx) = o;
    } else {
        if (idx     < N) { rowptr[idx]     = ex;               rp2[idx]     = ex; }
        if (idx + 1 < N) { rowptr[idx + 1] = ex + v0;          rp2[idx + 1] = ex + v0; }
        if (idx + 2 < N) { rowptr[idx + 2] = ex + v0 + v1;     rp2[idx + 2] = ex + v0 + v1; }
        if (idx + 3 < N) { rowptr[idx + 3] = ex + v0 + v1 + v2; rp2[idx + 3] = ex + v0 + v1 + v2; }
    }
}

// scatter: 1 atomic (allocator = rp2) + 1 write per edge
__global__ void csr_fill_kernel(const int* __restrict__ ei, const float* __restrict__ ew,
                                int* __restrict__ rp2, int2* __restrict__ csr, int E) {
    int e = blockIdx.x * blockDim.x + threadIdx.x;
    if (e >= E) return;
    int r = ei[e];
    int c = ei[E + e];
    int pos = atomicAdd(&rp2[c], 1);
    csr[pos] = make_int2(r, __float_as_int(ew[e]));
}

// per-row weighted degree (coalesced-ish linear read) -> dis, rowse
__global__ void row_stats_kernel(const int2* __restrict__ csr, const int* __restrict__ rowptr,
                                 float* __restrict__ dis, int2* __restrict__ rowse, int N) {
    int n = blockIdx.x * blockDim.x + threadIdx.x;
    if (n >= N) return;
    int s = rowptr[n], e = rowptr[n + 1];
    float deg = 1.0f;                       // self-loop
    for (int i = s; i < e; i++) deg += __int_as_float(csr[i].y);
    dis[n] = rsqrtf(deg);
    rowse[n] = make_int2(s, e);
}

// ---------------- encoder: stores s = dis * h_enc ----------------

__global__ __launch_bounds__(256, 4) void encoder_kernel(
    const float* __restrict__ x, const float* __restrict__ dis,
    const float* __restrict__ w1, const float* __restrict__ b1,
    const float* __restrict__ w2, const float* __restrict__ b2,
    unsigned short* __restrict__ hout, int N) {
    int lane = threadIdx.x & 63;
    int wid = __builtin_amdgcn_readfirstlane((blockIdx.x * blockDim.x + threadIdx.x) >> 6);
    int n0 = wid * 4;
    if (n0 >= N) return;

    float w2col[DEMB];
    #pragma unroll
    for (int k = 0; k < DEMB; k++) w2col[k] = w2[k * DEMB + lane];
    float w1a = w1[lane], w1b = w1[DEMB + lane];
    float b1v = b1[lane], b2v = b2[lane];

    float xv = 0.0f;
    if (lane < 8 && n0 * 2 + lane < 2 * N) xv = x[n0 * 2 + lane];

    #pragma unroll
    for (int m = 0; m < 4; m++) {
        int node = n0 + m;
        if (node >= N) continue;
        float x0 = rdlane(xv, 2 * m);
        float x1 = rdlane(xv, 2 * m + 1);
        float t = fmaxf(0.0f, fmaf(x0, w1a, fmaf(x1, w1b, b1v)));
        float y = b2v;
        #pragma unroll
        for (int k = 0; k < DEMB; k++)
            y = fmaf(rdlane(t, k), w2col[k], y);
        hout[(size_t)node * DEMB + lane] = f2bf(y * dis[node]);  // scaled state
    }
}

// ------- fused layer: 2 nodes/wave, paired gathers, masked unroll-16-edges -------
// s_in = dis*h;  agg = dis_c*(Σ ew*s_src + s_c);  h' = relu(agg·W + b); store (scaleOut? dis_c:1)*h'

__global__ __launch_bounds__(256, 6) void layer_kernel(
    const unsigned short* __restrict__ hin, const int2* __restrict__ csr,
    const int2* __restrict__ rowse, const float* __restrict__ dis,
    const float* __restrict__ W, const float* __restrict__ bias,
    unsigned short* __restrict__ hout, int N, int scaleOut) {
    int lane = threadIdx.x & 63;
    int wid = __builtin_amdgcn_readfirstlane((blockIdx.x * blockDim.x + threadIdx.x) >> 6);
    int n0 = wid * 2;
    if (n0 >= N) return;

    const unsigned int* hin32 = (const unsigned int*)hin;   // 2 bf16 per dword
    int p = lane >> 5;        // edge parity handled by this half-wave
    int q = lane & 31;        // feature-pair index (features 2q, 2q+1)
    float bv = bias[lane];

    float2 acc[2];
    #pragma unroll
    for (int m = 0; m < 2; m++) {
        int node = n0 + m;
        if (node >= N) { acc[m] = make_float2(0.0f, 0.0f); continue; }
        unsigned int su = hin32[(size_t)node * 32 + q];
        float2 a;
        a.x = (p == 0) ? bf2f((unsigned short)(su & 0xffff)) : 0.0f;
        a.y = (p == 0) ? bf2f((unsigned short)(su >> 16)) : 0.0f;
        int2 se = rowse[node];
        int s = se.x, e = se.y;
        // masked unroll: 16 edges per iteration, 8 csr loads + 8 gathers in flight
        for (int i = s; i < e; i += 16) {
            int   src[8];
            float wv[8];
            #pragma unroll
            for (int j = 0; j < 8; j++) {
                int t = i + 2 * j + p;
                int ic = (t < e) ? t : (e - 1);   // clamp: stays inside this row
                int2 en = csr[ic];
                src[j] = en.x;
                wv[j] = (t < e) ? __int_as_float(en.y) : 0.0f;
            }
            unsigned int u[8];
            #pragma unroll
            for (int j = 0; j < 8; j++)
                u[j] = hin32[(size_t)src[j] * 32 + q];
            #pragma unroll
            for (int j = 0; j < 8; j++) {
                a.x = fmaf(wv[j], bf2f((unsigned short)(u[j] & 0xffff)), a.x);
                a.y = fmaf(wv[j], bf2f((unsigned short)(u[j] >> 16)), a.y);
            }
        }
        // combine half-wave partials
        a.x += __shfl_xor(a.x, 32);
        a.y += __shfl_xor(a.y, 32);
        acc[m] = a;
    }

    #pragma unroll
    for (int m = 0; m < 2; m++) {
        int node = n0 + m;
        if (node >= N) continue;
        float d = dis[node];
        // 4 independent FMA chains to shorten the dependent path
        float dot0 = 0.0f, dot1 = 0.0f, dot2 = 0.0f, dot3 = 0.0f;
        #pragma unroll
        for (int kk = 0; kk < 8; kk++) {
            dot0 = fmaf(rdlane(acc[m].x, kk),      W[(2 * kk) * DEMB + lane],          dot0);
            dot1 = fmaf(rdlane(acc[m].y, kk),      W[(2 * kk + 1) * DEMB + lane],      dot1);
            dot2 = fmaf(rdlane(acc[m].x, kk + 8),  W[(2 * kk + 16) * DEMB + lane],     dot2);
            dot3 = fmaf(rdlane(acc[m].y, kk + 8),  W[(2 * kk + 17) * DEMB + lane],     dot3);
        }
        #pragma unroll
        for (int kk = 16; kk < 24; kk++) {
            dot0 = fmaf(rdlane(acc[m].x, kk),      W[(2 * kk) * DEMB + lane],          dot0);
            dot1 = fmaf(rdlane(acc[m].y, kk),      W[(2 * kk + 1) * DEMB + lane],      dot1);
            dot2 = fmaf(rdlane(acc[m].x, kk + 8),  W[(2 * kk + 16) * DEMB + lane],     dot2);
            dot3 = fmaf(rdlane(acc[m].y, kk + 8),  W[(2 * kk + 17) * DEMB + lane],     dot3);
        }
        float dot = (dot0 + dot1) + (dot2 + dot3);
        float y = fmaxf(fmaf(d, dot, bv), 0.0f);
        float os = scaleOut ? d : 1.0f;
        hout[(size_t)node * DEMB + lane] = f2bf(y * os);
    }
}

// ---------------- decoder + softmax + residual ----------------

__global__ __launch_bounds__(256, 4) void decoder_kernel(
    const unsigned short* __restrict__ h, const float* __restrict__ x,
    const float* __restrict__ dw1, const float* __restrict__ db1,
    const float* __restrict__ dw2, const float* __restrict__ db2,
    float* __restrict__ out, int N) {
    int lane = threadIdx.x & 63;
    int wid = __builtin_amdgcn_readfirstlane((blockIdx.x * blockDim.x + threadIdx.x) >> 6);
    int n0 = wid * 4;
    if (n0 >= N) return;

    float w1col[DEMB];
    #pragma unroll
    for (int k = 0; k < DEMB; k++) w1col[k] = dw1[k * DEMB + lane];
    float db1v = db1[lane];
    float w20 = dw2[lane * 2], w21 = dw2[lane * 2 + 1];
    float db20 = db2[0], db21 = db2[1];

    float xv = 0.0f;
    if (lane < 8 && n0 * 2 + lane < 2 * N) xv = x[n0 * 2 + lane];

    float myout = 0.0f;
    #pragma unroll
    for (int m = 0; m < 4; m++) {
        int node = n0 + m;
        if (node >= N) continue;
        float hv = bf2f(h[(size_t)node * DEMB + lane]);
        float y = db1v;
        #pragma unroll
        for (int k = 0; k < DEMB; k++)
            y = fmaf(rdlane(hv, k), w1col[k], y);
        float d1 = fmaxf(y, 0.0f);
        float p0 = d1 * w20, p1 = d1 * w21;
        #pragma unroll
        for (int off = 32; off > 0; off >>= 1) {
            p0 += __shfl_xor(p0, off);
            p1 += __shfl_xor(p1, off);
        }
        float o0 = p0 + db20, o1 = p1 + db21;
        float mm = fmaxf(o0, o1);
        float e0 = __expf(o0 - mm), e1 = __expf(o1 - mm);
        float inv = 1.0f / (e0 + e1);
        float r0 = e0 * inv + 2.0f * rdlane(xv, 2 * m);   // wc = [2, 0]
        float r1 = e1 * inv;
        if (lane == 2 * m) myout = r0;
        if (lane == 2 * m + 1) myout = r1;
    }
    if (lane < 8 && n0 * 2 + lane < 2 * N)
        out[n0 * 2 + lane] = myout;
}

// ---------------- launch ----------------

extern "C" void kernel_launch(void* const* d_in, const int* in_sizes, int n_in,
                              void* d_out, int out_size, void* d_ws, size_t ws_size,
                              hipStream_t stream) {
    const float* x      = (const float*)d_in[0];
    const int*   ei     = (const int*)d_in[1];
    const float* ew     = (const float*)d_in[2];
    const float* enc_w1 = (const float*)d_in[3];
    const float* enc_b1 = (const float*)d_in[4];
    const float* enc_w2 = (const float*)d_in[5];
    const float* enc_b2 = (const float*)d_in[6];
    const float* gcn_w  = (const float*)d_in[7];
    const float* gcn_b  = (const float*)d_in[8];
    const float* dec_w1 = (const float*)d_in[9];
    const float* dec_b1 = (const float*)d_in[10];
    const float* dec_w2 = (const float*)d_in[11];
    const float* dec_b2 = (const float*)d_in[12];
    float* out = (float*)d_out;

    const int N = in_sizes[0] / 2;
    const int E = in_sizes[2];
    const int L = in_sizes[7] / (DEMB * DEMB);

    // workspace layout (256B aligned)
    char* ws = (char*)d_ws;
    size_t o = 0;
    auto alignup = [](size_t v) { return (v + 255) & ~(size_t)255; };
    unsigned short* hA = (unsigned short*)(ws + o); o = alignup(o + (size_t)N * DEMB * 2);
    unsigned short* hB = (unsigned short*)(ws + o); o = alignup(o + (size_t)N * DEMB * 2);
    float* dis    = (float*)(ws + o); o = alignup(o + (size_t)N * 4);
    int*   cnt    = (int*)(ws + o);   o = alignup(o + (size_t)N * 4);
    int*   rowptr = (int*)(ws + o);   o = alignup(o + (size_t)(N + 1) * 4);
    int*   rp2    = (int*)(ws + o);   o = alignup(o + (size_t)N * 4);
    int2*  rowse  = (int2*)(ws + o);  o = alignup(o + (size_t)N * 8);
    int*   part   = (int*)(ws + o);   o = alignup(o + (size_t)1024 * 4);
    int2*  csr    = (int2*)(ws + o);  o = alignup(o + (size_t)E * 8);

    const int TB = 256;
    dim3 blk(TB);
    dim3 gN((N + TB - 1) / TB);
    dim3 gE((E + TB - 1) / TB);
    int NB = (N + 1023) >> 10;
    dim3 gWave2((N * 32 + TB - 1) / TB);    // wave per 2 nodes
    dim3 gWave4((N * 16 + TB - 1) / TB);    // wave per 4 nodes

    init_cnt_kernel<<<gN, blk, 0, stream>>>(cnt, N);
    hist_kernel<<<gE, blk, 0, stream>>>(ei, cnt, E);
    scan_sums_kernel<<<NB, blk, 0, stream>>>(cnt, part, N);
    scan_offsets_kernel<<<1, 1024, 0, stream>>>(part, rowptr, NB, N);
    scan_apply_kernel<<<NB, blk, 0, stream>>>(cnt, part, rowptr, rp2, N);
    csr_fill_kernel<<<gE, blk, 0, stream>>>(ei, ew, rp2, csr, E);
    row_stats_kernel<<<gN, blk, 0, stream>>>(csr, rowptr, dis, rowse, N);

    encoder_kernel<<<gWave4, blk, 0, stream>>>(x, dis, enc_w1, enc_b1, enc_w2, enc_b2, hA, N);

    unsigned short* hin = hA;
    unsigned short* hout = hB;
    for (int l = 0; l < L; l++) {
        layer_kernel<<<gWave2, blk, 0, stream>>>(hin, csr, rowse, dis,
                                                 gcn_w + (size_t)l * DEMB * DEMB,
                                                 gcn_b + (size_t)l * DEMB, hout, N,
                                                 (l < L - 1) ? 1 : 0);
        unsigned short* t = hin; hin = hout; hout = t;
    }

    decoder_kernel<<<gWave4, blk, 0, stream>>>(hin, x, dec_w1, dec_b1, dec_w2, dec_b2, out, N);
}

// Round 7
// 573.101 us; speedup vs baseline: 1.2473x; 1.2391x over previous
//
#include <hip/hip_runtime.h>
#include <hip/hip_bf16.h>
#include <math.h>

#define DEMB 64

typedef float v2f __attribute__((ext_vector_type(2)));

// ---------------- helpers ----------------

__device__ __forceinline__ float rdlane(float v, int k) {
    return __int_as_float(__builtin_amdgcn_readlane(__float_as_int(v), k));
}

// pack 64 lanes' y (feature=lane) into fp8 row; lanes 0..15 store one dword each
__device__ __forceinline__ void pack_store_fp8(float y, unsigned int* __restrict__ dst, int lane) {
    float y0 = __shfl(y, 4 * lane + 0);
    float y1 = __shfl(y, 4 * lane + 1);
    float y2 = __shfl(y, 4 * lane + 2);
    float y3 = __shfl(y, 4 * lane + 3);
    int u = __builtin_amdgcn_cvt_pk_fp8_f32(y0, y1, 0, false);
    u = __builtin_amdgcn_cvt_pk_fp8_f32(y2, y3, u, true);
    if (lane < 16) dst[lane] = (unsigned int)u;
}

// ---------------- graph preprocessing (unchanged from R6) ----------------

__global__ void init_cnt_kernel(int* __restrict__ cnt, int N) {
    int i = blockIdx.x * blockDim.x + threadIdx.x;
    if (i < N) cnt[i] = 0;
}

__global__ void hist_kernel(const int* __restrict__ ei, int* __restrict__ cnt, int E) {
    int e = blockIdx.x * blockDim.x + threadIdx.x;
    if (e >= E) return;
    atomicAdd(&cnt[ei[E + e]], 1);
}

__global__ __launch_bounds__(256) void scan_sums_kernel(const int* __restrict__ cnt,
                                                        int* __restrict__ part, int N) {
    int b = blockIdx.x, t = threadIdx.x, lane = t & 63, w = t >> 6;
    int idx = b * 1024 + t * 4;
    int s = 0;
    if (idx + 3 < N) {
        int4 v = *(const int4*)(cnt + idx);
        s = v.x + v.y + v.z + v.w;
    } else {
        for (int j = 0; j < 4; j++) if (idx + j < N) s += cnt[idx + j];
    }
    #pragma unroll
    for (int off = 32; off > 0; off >>= 1) s += __shfl_down(s, off);
    __shared__ int wt[4];
    if (lane == 0) wt[w] = s;
    __syncthreads();
    if (t == 0) part[b] = wt[0] + wt[1] + wt[2] + wt[3];
}

__global__ void scan_offsets_kernel(int* __restrict__ part, int* __restrict__ rowptr,
                                    int NB, int N) {
    __shared__ int sh[1024];
    int t = threadIdx.x;
    int mine = (t < NB) ? part[t] : 0;
    sh[t] = mine;
    __syncthreads();
    for (int off = 1; off < 1024; off <<= 1) {
        int v = (t >= off) ? sh[t - off] : 0;
        __syncthreads();
        sh[t] += v;
        __syncthreads();
    }
    if (t < NB) part[t] = sh[t] - mine;   // exclusive
    if (t == 1023) rowptr[N] = sh[1023];  // total = E
}

__global__ __launch_bounds__(256) void scan_apply_kernel(const int* __restrict__ cnt,
                                                         const int* __restrict__ part,
                                                         int* __restrict__ rowptr,
                                                         int* __restrict__ rp2, int N) {
    int b = blockIdx.x, t = threadIdx.x, lane = t & 63, w = t >> 6;
    int idx = b * 1024 + t * 4;
    int v0 = 0, v1 = 0, v2 = 0, v3 = 0;
    if (idx + 3 < N) {
        int4 v = *(const int4*)(cnt + idx);
        v0 = v.x; v1 = v.y; v2 = v.z; v3 = v.w;
    } else {
        if (idx     < N) v0 = cnt[idx];
        if (idx + 1 < N) v1 = cnt[idx + 1];
        if (idx + 2 < N) v2 = cnt[idx + 2];
        if (idx + 3 < N) v3 = cnt[idx + 3];
    }
    int tsum = v0 + v1 + v2 + v3;
    int sc = tsum;
    #pragma unroll
    for (int off = 1; off < 64; off <<= 1) {
        int u = __shfl_up(sc, off);
        if (lane >= off) sc += u;
    }
    __shared__ int wt[4];
    if (lane == 63) wt[w] = sc;
    __syncthreads();
    int woff = 0;
    for (int i = 0; i < w; i++) woff += wt[i];
    int ex = part[b] + woff + sc - tsum;
    if (idx + 3 < N) {
        int4 o;
        o.x = ex; o.y = ex + v0; o.z = ex + v0 + v1; o.w = ex + v0 + v1 + v2;
        *(int4*)(rowptr + idx) = o;
        *(int4*)(rp2 + idx) = o;
    } else {
        if (idx     < N) { rowptr[idx]     = ex;                rp2[idx]     = ex; }
        if (idx + 1 < N) { rowptr[idx + 1] = ex + v0;           rp2[idx + 1] = ex + v0; }
        if (idx + 2 < N) { rowptr[idx + 2] = ex + v0 + v1;      rp2[idx + 2] = ex + v0 + v1; }
        if (idx + 3 < N) { rowptr[idx + 3] = ex + v0 + v1 + v2; rp2[idx + 3] = ex + v0 + v1 + v2; }
    }
}

__global__ void csr_fill_kernel(const int* __restrict__ ei, const float* __restrict__ ew,
                                int* __restrict__ rp2, int2* __restrict__ csr, int E) {
    int e = blockIdx.x * blockDim.x + threadIdx.x;
    if (e >= E) return;
    int r = ei[e];
    int c = ei[E + e];
    int pos = atomicAdd(&rp2[c], 1);
    csr[pos] = make_int2(r, __float_as_int(ew[e]));
}

__global__ void row_stats_kernel(const int2* __restrict__ csr, const int* __restrict__ rowptr,
                                 float* __restrict__ dis, int2* __restrict__ rowse, int N) {
    int n = blockIdx.x * blockDim.x + threadIdx.x;
    if (n >= N) return;
    int s = rowptr[n], e = rowptr[n + 1];
    float deg = 1.0f;                       // self-loop
    for (int i = s; i < e; i++) deg += __int_as_float(csr[i].y);
    dis[n] = rsqrtf(deg);
    rowse[n] = make_int2(s, e);
}

// ---------------- encoder: stores s = dis * h_enc as fp8 ----------------

__global__ __launch_bounds__(256, 4) void encoder_kernel(
    const float* __restrict__ x, const float* __restrict__ dis,
    const float* __restrict__ w1, const float* __restrict__ b1,
    const float* __restrict__ w2, const float* __restrict__ b2,
    unsigned int* __restrict__ hout4, int N) {
    int lane = threadIdx.x & 63;
    int wid = __builtin_amdgcn_readfirstlane((blockIdx.x * blockDim.x + threadIdx.x) >> 6);
    int n0 = wid * 4;
    if (n0 >= N) return;

    float w2col[DEMB];
    #pragma unroll
    for (int k = 0; k < DEMB; k++) w2col[k] = w2[k * DEMB + lane];
    float w1a = w1[lane], w1b = w1[DEMB + lane];
    float b1v = b1[lane], b2v = b2[lane];

    float xv = 0.0f;
    if (lane < 8 && n0 * 2 + lane < 2 * N) xv = x[n0 * 2 + lane];

    #pragma unroll
    for (int m = 0; m < 4; m++) {
        int node = n0 + m;
        if (node >= N) continue;
        float x0 = rdlane(xv, 2 * m);
        float x1 = rdlane(xv, 2 * m + 1);
        float t = fmaxf(0.0f, fmaf(x0, w1a, fmaf(x1, w1b, b1v)));
        float y = b2v;
        #pragma unroll
        for (int k = 0; k < DEMB; k++)
            y = fmaf(rdlane(t, k), w2col[k], y);
        pack_store_fp8(y * dis[node], hout4 + (size_t)node * 16, lane);
    }
}

// ------- fused layer: wave per node, quad gathers on fp8 rows -------
// lane = (p = lane>>4 in 0..3 edge slot, q = lane&15 feature quad)
// agg = dis_c*(Σ ew*s_src + s_c);  h' = relu(agg·W + b); store fp8 (scaleOut? dis_c:1)*h'

__global__ __launch_bounds__(256, 6) void layer_kernel(
    const unsigned int* __restrict__ hin4, const int2* __restrict__ csr,
    const int2* __restrict__ rowse, const float* __restrict__ dis,
    const float* __restrict__ W, const float* __restrict__ bias,
    unsigned int* __restrict__ hout4, int N, int scaleOut) {
    int lane = threadIdx.x & 63;
    int n = __builtin_amdgcn_readfirstlane((blockIdx.x * blockDim.x + threadIdx.x) >> 6);
    if (n >= N) return;

    int p = lane >> 4;        // edge slot within quad (0..3)
    int q = lane & 15;        // feature quad (features 4q..4q+3)

    // self-loop term (counted once: p==0 only)
    unsigned int su = hin4[(size_t)n * 16 + q];
    float sw = (p == 0) ? 1.0f : 0.0f;
    v2f slo = __builtin_amdgcn_cvt_pk_f32_fp8((int)su, false);
    v2f shi = __builtin_amdgcn_cvt_pk_f32_fp8((int)su, true);
    float a0 = slo.x * sw, a1 = slo.y * sw, a2 = shi.x * sw, a3 = shi.y * sw;

    int2 se = rowse[n];
    int s = se.x, e = se.y;
    for (int i = s; i < e; i += 32) {
        // coalesced meta load: 32 entries, both half-waves mirror
        int t32 = i + (lane & 31);
        int2 mv = (t32 < e) ? csr[t32] : make_int2(0, 0);
        // distribute meta to slots: edge i+4j+p held by meta-lane 4j+p
        int   srcj[8];
        float wj[8];
        #pragma unroll
        for (int j = 0; j < 8; j++) {
            srcj[j] = __shfl(mv.x, 4 * j + p);
            wj[j]   = __int_as_float(__shfl(mv.y, 4 * j + p));
        }
        unsigned int u[8];
        #pragma unroll
        for (int j = 0; j < 8; j++)
            u[j] = hin4[(size_t)srcj[j] * 16 + q];
        #pragma unroll
        for (int j = 0; j < 8; j++) {
            v2f lo = __builtin_amdgcn_cvt_pk_f32_fp8((int)u[j], false);
            v2f hi = __builtin_amdgcn_cvt_pk_f32_fp8((int)u[j], true);
            a0 = fmaf(wj[j], lo.x, a0);
            a1 = fmaf(wj[j], lo.y, a1);
            a2 = fmaf(wj[j], hi.x, a2);
            a3 = fmaf(wj[j], hi.y, a3);
        }
    }
    // combine 4 edge-slot partials
    a0 += __shfl_xor(a0, 16); a0 += __shfl_xor(a0, 32);
    a1 += __shfl_xor(a1, 16); a1 += __shfl_xor(a1, 32);
    a2 += __shfl_xor(a2, 16); a2 += __shfl_xor(a2, 32);
    a3 += __shfl_xor(a3, 16); a3 += __shfl_xor(a3, 32);

    // transform: y[lane] = relu(dis * (agg · W[:,lane]) + b[lane])
    float d = dis[n];
    float dot0 = 0.0f, dot1 = 0.0f, dot2 = 0.0f, dot3 = 0.0f;
    #pragma unroll
    for (int kq = 0; kq < 16; kq++) {
        dot0 = fmaf(rdlane(a0, kq), W[(4 * kq + 0) * DEMB + lane], dot0);
        dot1 = fmaf(rdlane(a1, kq), W[(4 * kq + 1) * DEMB + lane], dot1);
        dot2 = fmaf(rdlane(a2, kq), W[(4 * kq + 2) * DEMB + lane], dot2);
        dot3 = fmaf(rdlane(a3, kq), W[(4 * kq + 3) * DEMB + lane], dot3);
    }
    float dot = (dot0 + dot1) + (dot2 + dot3);
    float y = fmaxf(fmaf(d, dot, bias[lane]), 0.0f);
    float os = scaleOut ? d : 1.0f;
    pack_store_fp8(y * os, hout4 + (size_t)n * 16, lane);
}

// ---------------- decoder + softmax + residual ----------------

__global__ __launch_bounds__(256, 4) void decoder_kernel(
    const unsigned char* __restrict__ h8, const float* __restrict__ x,
    const float* __restrict__ dw1, const float* __restrict__ db1,
    const float* __restrict__ dw2, const float* __restrict__ db2,
    float* __restrict__ out, int N) {
    int lane = threadIdx.x & 63;
    int wid = __builtin_amdgcn_readfirstlane((blockIdx.x * blockDim.x + threadIdx.x) >> 6);
    int n0 = wid * 4;
    if (n0 >= N) return;

    float w1col[DEMB];
    #pragma unroll
    for (int k = 0; k < DEMB; k++) w1col[k] = dw1[k * DEMB + lane];
    float db1v = db1[lane];
    float w20 = dw2[lane * 2], w21 = dw2[lane * 2 + 1];
    float db20 = db2[0], db21 = db2[1];

    float xv = 0.0f;
    if (lane < 8 && n0 * 2 + lane < 2 * N) xv = x[n0 * 2 + lane];

    float myout = 0.0f;
    #pragma unroll
    for (int m = 0; m < 4; m++) {
        int node = n0 + m;
        if (node >= N) continue;
        float hv = __builtin_amdgcn_cvt_f32_fp8((int)h8[(size_t)node * 64 + lane], 0);
        float y = db1v;
        #pragma unroll
        for (int k = 0; k < DEMB; k++)
            y = fmaf(rdlane(hv, k), w1col[k], y);
        float d1 = fmaxf(y, 0.0f);
        float p0 = d1 * w20, p1 = d1 * w21;
        #pragma unroll
        for (int off = 32; off > 0; off >>= 1) {
            p0 += __shfl_xor(p0, off);
            p1 += __shfl_xor(p1, off);
        }
        float o0 = p0 + db20, o1 = p1 + db21;
        float mm = fmaxf(o0, o1);
        float e0 = __expf(o0 - mm), e1 = __expf(o1 - mm);
        float inv = 1.0f / (e0 + e1);
        float r0 = e0 * inv + 2.0f * rdlane(xv, 2 * m);   // wc = [2, 0]
        float r1 = e1 * inv;
        if (lane == 2 * m) myout = r0;
        if (lane == 2 * m + 1) myout = r1;
    }
    if (lane < 8 && n0 * 2 + lane < 2 * N)
        out[n0 * 2 + lane] = myout;
}

// ---------------- launch ----------------

extern "C" void kernel_launch(void* const* d_in, const int* in_sizes, int n_in,
                              void* d_out, int out_size, void* d_ws, size_t ws_size,
                              hipStream_t stream) {
    const float* x      = (const float*)d_in[0];
    const int*   ei     = (const int*)d_in[1];
    const float* ew     = (const float*)d_in[2];
    const float* enc_w1 = (const float*)d_in[3];
    const float* enc_b1 = (const float*)d_in[4];
    const float* enc_w2 = (const float*)d_in[5];
    const float* enc_b2 = (const float*)d_in[6];
    const float* gcn_w  = (const float*)d_in[7];
    const float* gcn_b  = (const float*)d_in[8];
    const float* dec_w1 = (const float*)d_in[9];
    const float* dec_b1 = (const float*)d_in[10];
    const float* dec_w2 = (const float*)d_in[11];
    const float* dec_b2 = (const float*)d_in[12];
    float* out = (float*)d_out;

    const int N = in_sizes[0] / 2;
    const int E = in_sizes[2];
    const int L = in_sizes[7] / (DEMB * DEMB);

    // workspace layout (256B aligned); h rows are 64 B fp8
    char* ws = (char*)d_ws;
    size_t o = 0;
    auto alignup = [](size_t v) { return (v + 255) & ~(size_t)255; };
    unsigned int* hA = (unsigned int*)(ws + o); o = alignup(o + (size_t)N * DEMB);
    unsigned int* hB = (unsigned int*)(ws + o); o = alignup(o + (size_t)N * DEMB);
    float* dis    = (float*)(ws + o); o = alignup(o + (size_t)N * 4);
    int*   cnt    = (int*)(ws + o);   o = alignup(o + (size_t)N * 4);
    int*   rowptr = (int*)(ws + o);   o = alignup(o + (size_t)(N + 1) * 4);
    int*   rp2    = (int*)(ws + o);   o = alignup(o + (size_t)N * 4);
    int2*  rowse  = (int2*)(ws + o);  o = alignup(o + (size_t)N * 8);
    int*   part   = (int*)(ws + o);   o = alignup(o + (size_t)1024 * 4);
    int2*  csr    = (int2*)(ws + o);  o = alignup(o + (size_t)E * 8);

    const int TB = 256;
    dim3 blk(TB);
    dim3 gN((N + TB - 1) / TB);
    dim3 gE((E + TB - 1) / TB);
    int NB = (N + 1023) >> 10;
    dim3 gWave1((N * 64 + TB - 1) / TB);    // wave per node
    dim3 gWave4((N * 16 + TB - 1) / TB);    // wave per 4 nodes

    init_cnt_kernel<<<gN, blk, 0, stream>>>(cnt, N);
    hist_kernel<<<gE, blk, 0, stream>>>(ei, cnt, E);
    scan_sums_kernel<<<NB, blk, 0, stream>>>(cnt, part, N);
    scan_offsets_kernel<<<1, 1024, 0, stream>>>(part, rowptr, NB, N);
    scan_apply_kernel<<<NB, blk, 0, stream>>>(cnt, part, rowptr, rp2, N);
    csr_fill_kernel<<<gE, blk, 0, stream>>>(ei, ew, rp2, csr, E);
    row_stats_kernel<<<gN, blk, 0, stream>>>(csr, rowptr, dis, rowse, N);

    encoder_kernel<<<gWave4, blk, 0, stream>>>(x, dis, enc_w1, enc_b1, enc_w2, enc_b2, hA, N);

    unsigned int* hin = hA;
    unsigned int* hout = hB;
    for (int l = 0; l < L; l++) {
        layer_kernel<<<gWave1, blk, 0, stream>>>(hin, csr, rowse, dis,
                                                 gcn_w + (size_t)l * DEMB * DEMB,
                                                 gcn_b + (size_t)l * DEMB, hout, N,
                                                 (l < L - 1) ? 1 : 0);
        unsigned int* t = hin; hin = hout; hout = t;
    }

    decoder_kernel<<<gWave4, blk, 0, stream>>>((const unsigned char*)hin, x,
                                               dec_w1, dec_b1, dec_w2, dec_b2, out, N);
}

// Round 8
// 451.614 us; speedup vs baseline: 1.5829x; 1.2690x over previous
//
#include <hip/hip_runtime.h>
#include <hip/hip_bf16.h>
#include <math.h>

#define DEMB 64
#define NPBKT 256          // nodes per coarse bucket (c >> 8)
#define CHUNK_A 8192       // edges per pass-A workgroup
#define SENT_CAP 5632      // LDS staging entries in pass B (45 KB)

typedef float v2f __attribute__((ext_vector_type(2)));

// ---------------- helpers ----------------

__device__ __forceinline__ float rdlane(float v, int k) {
    return __int_as_float(__builtin_amdgcn_readlane(__float_as_int(v), k));
}

// pack 64 lanes' y (feature=lane) into fp8 row; lanes 0..15 store one dword each
__device__ __forceinline__ void pack_store_fp8(float y, unsigned int* __restrict__ dst, int lane) {
    float y0 = __shfl(y, 4 * lane + 0);
    float y1 = __shfl(y, 4 * lane + 1);
    float y2 = __shfl(y, 4 * lane + 2);
    float y3 = __shfl(y, 4 * lane + 3);
    int u = __builtin_amdgcn_cvt_pk_fp8_f32(y0, y1, 0, false);
    u = __builtin_amdgcn_cvt_pk_fp8_f32(y2, y3, u, true);
    if (lane < 16) dst[lane] = (unsigned int)u;
}

// ---------------- preprocessing: two-level LDS-staged counting sort ----------------

__global__ void init_bkt_kernel(int* __restrict__ bktcnt) {
    bktcnt[blockIdx.x * blockDim.x + threadIdx.x] = 0;   // grid sized to 1024 total
}

// pass A0: per-chunk LDS histogram of coarse buckets -> global bucket counts
__global__ __launch_bounds__(256) void histA_kernel(const int* __restrict__ ei,
                                                    int* __restrict__ bktcnt,
                                                    int E, int NBKT) {
    __shared__ int lh[1024];
    int t = threadIdx.x;
    for (int b = t; b < 1024; b += 256) lh[b] = 0;
    __syncthreads();
    int base = blockIdx.x * CHUNK_A;
    int end = base + CHUNK_A; if (end > E) end = E;
    for (int i = base + t; i < end; i += 256)
        atomicAdd(&lh[((unsigned int)ei[E + i]) >> 8], 1);
    __syncthreads();
    for (int b = t; b < NBKT; b += 256)
        if (lh[b]) atomicAdd(&bktcnt[b], lh[b]);
}

// single-block scan of bucket counts -> bktbase (exclusive, +sentinel), bktfill = base
__global__ void scanB_kernel(const int* __restrict__ bktcnt, int* __restrict__ bktbase,
                             int* __restrict__ bktfill, int NBKT) {
    __shared__ int sh[1024];
    int t = threadIdx.x;
    int mine = (t < NBKT) ? bktcnt[t] : 0;
    sh[t] = mine;
    __syncthreads();
    for (int off = 1; off < 1024; off <<= 1) {
        int v = (t >= off) ? sh[t - off] : 0;
        __syncthreads();
        sh[t] += v;
        __syncthreads();
    }
    if (t < NBKT) { bktbase[t] = sh[t] - mine; bktfill[t] = sh[t] - mine; }
    if (t == 1023) bktbase[NBKT] = sh[1023];   // total = E
}

// pass A1: re-histogram chunk, reserve per-bucket runs, scatter entries into runs.
// entry: x = (c&255)<<20 | r  (unsigned), y = bits(ew)
__global__ __launch_bounds__(256) void binA_kernel(const int* __restrict__ ei,
                                                   const float* __restrict__ ew,
                                                   int* __restrict__ bktfill,
                                                   int2* __restrict__ cells,
                                                   int E, int NBKT) {
    __shared__ int lh[1024];
    __shared__ int lbase[1024];
    __shared__ int lcur[1024];
    int t = threadIdx.x;
    for (int b = t; b < 1024; b += 256) { lh[b] = 0; lcur[b] = 0; }
    __syncthreads();
    int base = blockIdx.x * CHUNK_A;
    int end = base + CHUNK_A; if (end > E) end = E;
    for (int i = base + t; i < end; i += 256)
        atomicAdd(&lh[((unsigned int)ei[E + i]) >> 8], 1);
    __syncthreads();
    for (int b = t; b < NBKT; b += 256)
        if (lh[b]) lbase[b] = atomicAdd(&bktfill[b], lh[b]);
    __syncthreads();
    for (int i = base + t; i < end; i += 256) {
        unsigned int r = (unsigned int)ei[i];
        unsigned int c = (unsigned int)ei[E + i];
        int bkt = c >> 8;
        int pos = lbase[bkt] + atomicAdd(&lcur[bkt], 1);
        cells[pos] = make_int2((int)(((c & 255u) << 20) | r), __float_as_int(ew[i]));
    }
}

// pass B: per bucket — count + weighted degree, scan, write dis/rowse,
// sort entries into LDS, stream CSR out coalesced.
__global__ __launch_bounds__(256) void bucketB_kernel(
    const int2* __restrict__ cells, const int* __restrict__ bktbase,
    int2* __restrict__ csr, int2* __restrict__ rowse, float* __restrict__ dis, int N) {
    __shared__ int scnt[NPBKT];
    __shared__ float sdeg[NPBKT];
    __shared__ int sstart[NPBKT];
    __shared__ int sfill[NPBKT];
    __shared__ int ssc[NPBKT];
    __shared__ int2 sout[SENT_CAP];

    int b = blockIdx.x;
    int t = threadIdx.x;
    int nodebase = b << 8;
    int nNodes = N - nodebase; if (nNodes > NPBKT) nNodes = NPBKT;

    if (t < NPBKT) { scnt[t] = 0; sdeg[t] = 1.0f; sfill[t] = 0; }   // self-loop deg=1
    __syncthreads();

    int lo = bktbase[b], hi = bktbase[b + 1];
    int nent = hi - lo;

    // count + weighted degree
    for (int i = lo + t; i < hi; i += 256) {
        int2 en = cells[i];
        unsigned int ld = ((unsigned int)en.x) >> 20;
        atomicAdd(&scnt[ld], 1);
        atomicAdd(&sdeg[ld], __int_as_float(en.y));
    }
    __syncthreads();

    // exclusive scan of the 256 counts
    int mine = scnt[t];
    ssc[t] = mine;
    __syncthreads();
    for (int off = 1; off < NPBKT; off <<= 1) {
        int v = (t >= off) ? ssc[t - off] : 0;
        __syncthreads();
        ssc[t] += v;
        __syncthreads();
    }
    sstart[t] = ssc[t] - mine;
    __syncthreads();

    if (t < nNodes) {
        int node = nodebase + t;
        dis[node] = rsqrtf(sdeg[t]);
        rowse[node] = make_int2(lo + sstart[t], lo + sstart[t] + scnt[t]);
    }

    if (nent <= SENT_CAP) {
        for (int i = lo + t; i < hi; i += 256) {
            int2 en = cells[i];
            unsigned int ux = (unsigned int)en.x;
            unsigned int ld = ux >> 20;
            int pos = sstart[ld] + atomicAdd(&sfill[ld], 1);
            sout[pos] = make_int2((int)(ux & 0xFFFFFu), en.y);
        }
        __syncthreads();
        for (int i = t; i < nent; i += 256)
            csr[lo + i] = sout[i];
    } else {
        // fallback (pathological skew): direct global scatter
        for (int i = lo + t; i < hi; i += 256) {
            int2 en = cells[i];
            unsigned int ux = (unsigned int)en.x;
            unsigned int ld = ux >> 20;
            int pos = atomicAdd(&sfill[ld], 1);
            csr[lo + sstart[ld] + pos] = make_int2((int)(ux & 0xFFFFFu), en.y);
        }
    }
}

// ---------------- encoder: stores s = dis * h_enc as fp8 ----------------

__global__ __launch_bounds__(256, 4) void encoder_kernel(
    const float* __restrict__ x, const float* __restrict__ dis,
    const float* __restrict__ w1, const float* __restrict__ b1,
    const float* __restrict__ w2, const float* __restrict__ b2,
    unsigned int* __restrict__ hout4, int N) {
    int lane = threadIdx.x & 63;
    int wid = __builtin_amdgcn_readfirstlane((blockIdx.x * blockDim.x + threadIdx.x) >> 6);
    int n0 = wid * 4;
    if (n0 >= N) return;

    float w2col[DEMB];
    #pragma unroll
    for (int k = 0; k < DEMB; k++) w2col[k] = w2[k * DEMB + lane];
    float w1a = w1[lane], w1b = w1[DEMB + lane];
    float b1v = b1[lane], b2v = b2[lane];

    float xv = 0.0f;
    if (lane < 8 && n0 * 2 + lane < 2 * N) xv = x[n0 * 2 + lane];

    #pragma unroll
    for (int m = 0; m < 4; m++) {
        int node = n0 + m;
        if (node >= N) continue;
        float x0 = rdlane(xv, 2 * m);
        float x1 = rdlane(xv, 2 * m + 1);
        float t = fmaxf(0.0f, fmaf(x0, w1a, fmaf(x1, w1b, b1v)));
        float y = b2v;
        #pragma unroll
        for (int k = 0; k < DEMB; k++)
            y = fmaf(rdlane(t, k), w2col[k], y);
        pack_store_fp8(y * dis[node], hout4 + (size_t)node * 16, lane);
    }
}

// ------- fused layer: wave per node, quad gathers on fp8 rows -------

__global__ __launch_bounds__(256, 6) void layer_kernel(
    const unsigned int* __restrict__ hin4, const int2* __restrict__ csr,
    const int2* __restrict__ rowse, const float* __restrict__ dis,
    const float* __restrict__ W, const float* __restrict__ bias,
    unsigned int* __restrict__ hout4, int N, int scaleOut) {
    int lane = threadIdx.x & 63;
    int n = __builtin_amdgcn_readfirstlane((blockIdx.x * blockDim.x + threadIdx.x) >> 6);
    if (n >= N) return;

    int p = lane >> 4;        // edge slot within quad (0..3)
    int q = lane & 15;        // feature quad (features 4q..4q+3)

    unsigned int su = hin4[(size_t)n * 16 + q];
    float sw = (p == 0) ? 1.0f : 0.0f;
    v2f slo = __builtin_amdgcn_cvt_pk_f32_fp8((int)su, false);
    v2f shi = __builtin_amdgcn_cvt_pk_f32_fp8((int)su, true);
    float a0 = slo.x * sw, a1 = slo.y * sw, a2 = shi.x * sw, a3 = shi.y * sw;

    int2 se = rowse[n];
    int s = se.x, e = se.y;
    for (int i = s; i < e; i += 32) {
        int t32 = i + (lane & 31);
        int2 mv = (t32 < e) ? csr[t32] : make_int2(0, 0);
        int   srcj[8];
        float wj[8];
        #pragma unroll
        for (int j = 0; j < 8; j++) {
            srcj[j] = __shfl(mv.x, 4 * j + p);
            wj[j]   = __int_as_float(__shfl(mv.y, 4 * j + p));
        }
        unsigned int u[8];
        #pragma unroll
        for (int j = 0; j < 8; j++)
            u[j] = hin4[(size_t)srcj[j] * 16 + q];
        #pragma unroll
        for (int j = 0; j < 8; j++) {
            v2f lo = __builtin_amdgcn_cvt_pk_f32_fp8((int)u[j], false);
            v2f hi = __builtin_amdgcn_cvt_pk_f32_fp8((int)u[j], true);
            a0 = fmaf(wj[j], lo.x, a0);
            a1 = fmaf(wj[j], lo.y, a1);
            a2 = fmaf(wj[j], hi.x, a2);
            a3 = fmaf(wj[j], hi.y, a3);
        }
    }
    a0 += __shfl_xor(a0, 16); a0 += __shfl_xor(a0, 32);
    a1 += __shfl_xor(a1, 16); a1 += __shfl_xor(a1, 32);
    a2 += __shfl_xor(a2, 16); a2 += __shfl_xor(a2, 32);
    a3 += __shfl_xor(a3, 16); a3 += __shfl_xor(a3, 32);

    float d = dis[n];
    float dot0 = 0.0f, dot1 = 0.0f, dot2 = 0.0f, dot3 = 0.0f;
    #pragma unroll
    for (int kq = 0; kq < 16; kq++) {
        dot0 = fmaf(rdlane(a0, kq), W[(4 * kq + 0) * DEMB + lane], dot0);
        dot1 = fmaf(rdlane(a1, kq), W[(4 * kq + 1) * DEMB + lane], dot1);
        dot2 = fmaf(rdlane(a2, kq), W[(4 * kq + 2) * DEMB + lane], dot2);
        dot3 = fmaf(rdlane(a3, kq), W[(4 * kq + 3) * DEMB + lane], dot3);
    }
    float dot = (dot0 + dot1) + (dot2 + dot3);
    float y = fmaxf(fmaf(d, dot, bias[lane]), 0.0f);
    float os = scaleOut ? d : 1.0f;
    pack_store_fp8(y * os, hout4 + (size_t)n * 16, lane);
}

// ---------------- decoder + softmax + residual ----------------

__global__ __launch_bounds__(256, 4) void decoder_kernel(
    const unsigned char* __restrict__ h8, const float* __restrict__ x,
    const float* __restrict__ dw1, const float* __restrict__ db1,
    const float* __restrict__ dw2, const float* __restrict__ db2,
    float* __restrict__ out, int N) {
    int lane = threadIdx.x & 63;
    int wid = __builtin_amdgcn_readfirstlane((blockIdx.x * blockDim.x + threadIdx.x) >> 6);
    int n0 = wid * 4;
    if (n0 >= N) return;

    float w1col[DEMB];
    #pragma unroll
    for (int k = 0; k < DEMB; k++) w1col[k] = dw1[k * DEMB + lane];
    float db1v = db1[lane];
    float w20 = dw2[lane * 2], w21 = dw2[lane * 2 + 1];
    float db20 = db2[0], db21 = db2[1];

    float xv = 0.0f;
    if (lane < 8 && n0 * 2 + lane < 2 * N) xv = x[n0 * 2 + lane];

    float myout = 0.0f;
    #pragma unroll
    for (int m = 0; m < 4; m++) {
        int node = n0 + m;
        if (node >= N) continue;
        float hv = __builtin_amdgcn_cvt_f32_fp8((int)h8[(size_t)node * 64 + lane], 0);
        float y = db1v;
        #pragma unroll
        for (int k = 0; k < DEMB; k++)
            y = fmaf(rdlane(hv, k), w1col[k], y);
        float d1 = fmaxf(y, 0.0f);
        float p0 = d1 * w20, p1 = d1 * w21;
        #pragma unroll
        for (int off = 32; off > 0; off >>= 1) {
            p0 += __shfl_xor(p0, off);
            p1 += __shfl_xor(p1, off);
        }
        float o0 = p0 + db20, o1 = p1 + db21;
        float mm = fmaxf(o0, o1);
        float e0 = __expf(o0 - mm), e1 = __expf(o1 - mm);
        float inv = 1.0f / (e0 + e1);
        float r0 = e0 * inv + 2.0f * rdlane(xv, 2 * m);   // wc = [2, 0]
        float r1 = e1 * inv;
        if (lane == 2 * m) myout = r0;
        if (lane == 2 * m + 1) myout = r1;
    }
    if (lane < 8 && n0 * 2 + lane < 2 * N)
        out[n0 * 2 + lane] = myout;
}

// ---------------- launch ----------------

extern "C" void kernel_launch(void* const* d_in, const int* in_sizes, int n_in,
                              void* d_out, int out_size, void* d_ws, size_t ws_size,
                              hipStream_t stream) {
    const float* x      = (const float*)d_in[0];
    const int*   ei     = (const int*)d_in[1];
    const float* ew     = (const float*)d_in[2];
    const float* enc_w1 = (const float*)d_in[3];
    const float* enc_b1 = (const float*)d_in[4];
    const float* enc_w2 = (const float*)d_in[5];
    const float* enc_b2 = (const float*)d_in[6];
    const float* gcn_w  = (const float*)d_in[7];
    const float* gcn_b  = (const float*)d_in[8];
    const float* dec_w1 = (const float*)d_in[9];
    const float* dec_b1 = (const float*)d_in[10];
    const float* dec_w2 = (const float*)d_in[11];
    const float* dec_b2 = (const float*)d_in[12];
    float* out = (float*)d_out;

    const int N = in_sizes[0] / 2;
    const int E = in_sizes[2];
    const int L = in_sizes[7] / (DEMB * DEMB);
    const int NBKT = (N + NPBKT - 1) / NPBKT;

    // workspace layout (256B aligned); h rows are 64 B fp8
    char* ws = (char*)d_ws;
    size_t o = 0;
    auto alignup = [](size_t v) { return (v + 255) & ~(size_t)255; };
    unsigned int* hA = (unsigned int*)(ws + o); o = alignup(o + (size_t)N * DEMB);
    unsigned int* hB = (unsigned int*)(ws + o); o = alignup(o + (size_t)N * DEMB);
    float* dis     = (float*)(ws + o); o = alignup(o + (size_t)N * 4);
    int2*  rowse   = (int2*)(ws + o);  o = alignup(o + (size_t)N * 8);
    int*   bktcnt  = (int*)(ws + o);   o = alignup(o + (size_t)1024 * 4);
    int*   bktbase = (int*)(ws + o);   o = alignup(o + (size_t)1025 * 4);
    int*   bktfill = (int*)(ws + o);   o = alignup(o + (size_t)1024 * 4);
    int2*  cells   = (int2*)(ws + o);  o = alignup(o + (size_t)E * 8);
    int2*  csr     = (int2*)(ws + o);  o = alignup(o + (size_t)E * 8);

    const int TB = 256;
    dim3 blk(TB);
    int NWGA = (E + CHUNK_A - 1) / CHUNK_A;
    dim3 gWave1((N * 64 + TB - 1) / TB);    // wave per node
    dim3 gWave4((N * 16 + TB - 1) / TB);    // wave per 4 nodes

    init_bkt_kernel<<<4, blk, 0, stream>>>(bktcnt);
    histA_kernel<<<NWGA, blk, 0, stream>>>(ei, bktcnt, E, NBKT);
    scanB_kernel<<<1, 1024, 0, stream>>>(bktcnt, bktbase, bktfill, NBKT);
    binA_kernel<<<NWGA, blk, 0, stream>>>(ei, ew, bktfill, cells, E, NBKT);
    bucketB_kernel<<<NBKT, blk, 0, stream>>>(cells, bktbase, csr, rowse, dis, N);

    encoder_kernel<<<gWave4, blk, 0, stream>>>(x, dis, enc_w1, enc_b1, enc_w2, enc_b2, hA, N);

    unsigned int* hin = hA;
    unsigned int* hout = hB;
    for (int l = 0; l < L; l++) {
        layer_kernel<<<gWave1, blk, 0, stream>>>(hin, csr, rowse, dis,
                                                 gcn_w + (size_t)l * DEMB * DEMB,
                                                 gcn_b + (size_t)l * DEMB, hout, N,
                                                 (l < L - 1) ? 1 : 0);
        unsigned int* t = hin; hin = hout; hout = t;
    }

    decoder_kernel<<<gWave4, blk, 0, stream>>>((const unsigned char*)hin, x,
                                               dec_w1, dec_b1, dec_w2, dec_b2, out, N);
}

// Round 9
// 400.377 us; speedup vs baseline: 1.7855x; 1.1280x over previous
//
#include <hip/hip_runtime.h>
#include <hip/hip_bf16.h>
#include <math.h>

#define DEMB 64
#define NPBKT 256          // nodes per coarse bucket (c >> 8)
#define CHUNK_A 8192       // edges per pass-A workgroup
#define SENT_CAP 5632      // LDS staging entries in pass B (45 KB)

typedef float v2f __attribute__((ext_vector_type(2)));
typedef short short8 __attribute__((ext_vector_type(8)));
typedef float f32x4 __attribute__((ext_vector_type(4)));

// ---------------- helpers ----------------

__device__ __forceinline__ float rdlane(float v, int k) {
    return __int_as_float(__builtin_amdgcn_readlane(__float_as_int(v), k));
}
__device__ __forceinline__ unsigned int f2bf(float f) {
    union { float f; unsigned int i; } c; c.f = f;
    unsigned int r = c.i + 0x7FFFu + ((c.i >> 16) & 1u);   // RNE
    return r >> 16;
}

// pack 64 lanes' y (feature=lane) into fp8 row; lanes 0..15 store one dword each
__device__ __forceinline__ void pack_store_fp8(float y, unsigned int* __restrict__ dst, int lane) {
    float y0 = __shfl(y, 4 * lane + 0);
    float y1 = __shfl(y, 4 * lane + 1);
    float y2 = __shfl(y, 4 * lane + 2);
    float y3 = __shfl(y, 4 * lane + 3);
    int u = __builtin_amdgcn_cvt_pk_fp8_f32(y0, y1, 0, false);
    u = __builtin_amdgcn_cvt_pk_fp8_f32(y2, y3, u, true);
    if (lane < 16) dst[lane] = (unsigned int)u;
}

// ---------------- preprocessing: two-level LDS-staged counting sort ----------------

__global__ void init_bkt_kernel(int* __restrict__ bktcnt) {
    bktcnt[blockIdx.x * blockDim.x + threadIdx.x] = 0;   // grid sized to 1024 total
}

__global__ __launch_bounds__(256) void histA_kernel(const int* __restrict__ ei,
                                                    int* __restrict__ bktcnt,
                                                    int E, int NBKT) {
    __shared__ int lh[1024];
    int t = threadIdx.x;
    for (int b = t; b < 1024; b += 256) lh[b] = 0;
    __syncthreads();
    int base = blockIdx.x * CHUNK_A;
    int end = base + CHUNK_A; if (end > E) end = E;
    for (int i = base + t; i < end; i += 256)
        atomicAdd(&lh[((unsigned int)ei[E + i]) >> 8], 1);
    __syncthreads();
    for (int b = t; b < NBKT; b += 256)
        if (lh[b]) atomicAdd(&bktcnt[b], lh[b]);
}

__global__ void scanB_kernel(const int* __restrict__ bktcnt, int* __restrict__ bktbase,
                             int* __restrict__ bktfill, int NBKT) {
    __shared__ int sh[1024];
    int t = threadIdx.x;
    int mine = (t < NBKT) ? bktcnt[t] : 0;
    sh[t] = mine;
    __syncthreads();
    for (int off = 1; off < 1024; off <<= 1) {
        int v = (t >= off) ? sh[t - off] : 0;
        __syncthreads();
        sh[t] += v;
        __syncthreads();
    }
    if (t < NBKT) { bktbase[t] = sh[t] - mine; bktfill[t] = sh[t] - mine; }
    if (t == 1023) bktbase[NBKT] = sh[1023];   // total = E
}

__global__ __launch_bounds__(256) void binA_kernel(const int* __restrict__ ei,
                                                   const float* __restrict__ ew,
                                                   int* __restrict__ bktfill,
                                                   int2* __restrict__ cells,
                                                   int E, int NBKT) {
    __shared__ int lh[1024];
    __shared__ int lbase[1024];
    __shared__ int lcur[1024];
    int t = threadIdx.x;
    for (int b = t; b < 1024; b += 256) { lh[b] = 0; lcur[b] = 0; }
    __syncthreads();
    int base = blockIdx.x * CHUNK_A;
    int end = base + CHUNK_A; if (end > E) end = E;
    for (int i = base + t; i < end; i += 256)
        atomicAdd(&lh[((unsigned int)ei[E + i]) >> 8], 1);
    __syncthreads();
    for (int b = t; b < NBKT; b += 256)
        if (lh[b]) lbase[b] = atomicAdd(&bktfill[b], lh[b]);
    __syncthreads();
    for (int i = base + t; i < end; i += 256) {
        unsigned int r = (unsigned int)ei[i];
        unsigned int c = (unsigned int)ei[E + i];
        int bkt = c >> 8;
        int pos = lbase[bkt] + atomicAdd(&lcur[bkt], 1);
        cells[pos] = make_int2((int)(((c & 255u) << 20) | r), __float_as_int(ew[i]));
    }
}

__global__ __launch_bounds__(256) void bucketB_kernel(
    const int2* __restrict__ cells, const int* __restrict__ bktbase,
    int2* __restrict__ csr, int2* __restrict__ rowse, float* __restrict__ dis, int N) {
    __shared__ int scnt[NPBKT];
    __shared__ float sdeg[NPBKT];
    __shared__ int sstart[NPBKT];
    __shared__ int sfill[NPBKT];
    __shared__ int ssc[NPBKT];
    __shared__ int2 sout[SENT_CAP];

    int b = blockIdx.x;
    int t = threadIdx.x;
    int nodebase = b << 8;
    int nNodes = N - nodebase; if (nNodes > NPBKT) nNodes = NPBKT;

    if (t < NPBKT) { scnt[t] = 0; sdeg[t] = 1.0f; sfill[t] = 0; }   // self-loop deg=1
    __syncthreads();

    int lo = bktbase[b], hi = bktbase[b + 1];
    int nent = hi - lo;

    for (int i = lo + t; i < hi; i += 256) {
        int2 en = cells[i];
        unsigned int ld = ((unsigned int)en.x) >> 20;
        atomicAdd(&scnt[ld], 1);
        atomicAdd(&sdeg[ld], __int_as_float(en.y));
    }
    __syncthreads();

    int mine = scnt[t];
    ssc[t] = mine;
    __syncthreads();
    for (int off = 1; off < NPBKT; off <<= 1) {
        int v = (t >= off) ? ssc[t - off] : 0;
        __syncthreads();
        ssc[t] += v;
        __syncthreads();
    }
    sstart[t] = ssc[t] - mine;
    __syncthreads();

    if (t < nNodes) {
        int node = nodebase + t;
        dis[node] = rsqrtf(sdeg[t]);
        rowse[node] = make_int2(lo + sstart[t], lo + sstart[t] + scnt[t]);
    }

    if (nent <= SENT_CAP) {
        for (int i = lo + t; i < hi; i += 256) {
            int2 en = cells[i];
            unsigned int ux = (unsigned int)en.x;
            unsigned int ld = ux >> 20;
            int pos = sstart[ld] + atomicAdd(&sfill[ld], 1);
            sout[pos] = make_int2((int)(ux & 0xFFFFFu), en.y);
        }
        __syncthreads();
        for (int i = t; i < nent; i += 256)
            csr[lo + i] = sout[i];
    } else {
        for (int i = lo + t; i < hi; i += 256) {
            int2 en = cells[i];
            unsigned int ux = (unsigned int)en.x;
            unsigned int ld = ux >> 20;
            int pos = atomicAdd(&sfill[ld], 1);
            csr[lo + sstart[ld] + pos] = make_int2((int)(ux & 0xFFFFFu), en.y);
        }
    }
}

// ---------------- encoder: stores s = dis * h_enc as fp8 ----------------

__global__ __launch_bounds__(256, 4) void encoder_kernel(
    const float* __restrict__ x, const float* __restrict__ dis,
    const float* __restrict__ w1, const float* __restrict__ b1,
    const float* __restrict__ w2, const float* __restrict__ b2,
    unsigned int* __restrict__ hout4, int N) {
    int lane = threadIdx.x & 63;
    int wid = __builtin_amdgcn_readfirstlane((blockIdx.x * blockDim.x + threadIdx.x) >> 6);
    int n0 = wid * 4;
    if (n0 >= N) return;

    float w2col[DEMB];
    #pragma unroll
    for (int k = 0; k < DEMB; k++) w2col[k] = w2[k * DEMB + lane];
    float w1a = w1[lane], w1b = w1[DEMB + lane];
    float b1v = b1[lane], b2v = b2[lane];

    float xv = 0.0f;
    if (lane < 8 && n0 * 2 + lane < 2 * N) xv = x[n0 * 2 + lane];

    #pragma unroll
    for (int m = 0; m < 4; m++) {
        int node = n0 + m;
        if (node >= N) continue;
        float x0 = rdlane(xv, 2 * m);
        float x1 = rdlane(xv, 2 * m + 1);
        float t = fmaxf(0.0f, fmaf(x0, w1a, fmaf(x1, w1b, b1v)));
        float y = b2v;
        #pragma unroll
        for (int k = 0; k < DEMB; k++)
            y = fmaf(rdlane(t, k), w2col[k], y);
        pack_store_fp8(y * dis[node], hout4 + (size_t)node * 16, lane);
    }
}

// ------- aggregation: wave per node, quad gathers on fp8 rows, direct slot meta loads -------
// writes g = dis_c * (Σ ew*s_src + s_c) as bf16 row [64] (128 B)

__global__ __launch_bounds__(256, 6) void agg_kernel(
    const unsigned int* __restrict__ hin4, const int2* __restrict__ csr,
    const int2* __restrict__ rowse, const float* __restrict__ dis,
    unsigned int* __restrict__ Gout, int N) {
    int lane = threadIdx.x & 63;
    int n = __builtin_amdgcn_readfirstlane((blockIdx.x * blockDim.x + threadIdx.x) >> 6);
    if (n >= N) return;

    int p = lane >> 4;        // edge slot (0..3), interleaved stride-4
    int q = lane & 15;        // feature quad (features 4q..4q+3)

    unsigned int su = hin4[(size_t)n * 16 + q];
    float sw = (p == 0) ? 1.0f : 0.0f;
    v2f slo = __builtin_amdgcn_cvt_pk_f32_fp8((int)su, false);
    v2f shi = __builtin_amdgcn_cvt_pk_f32_fp8((int)su, true);
    float a0 = slo.x * sw, a1 = slo.y * sw, a2 = shi.x * sw, a3 = shi.y * sw;

    int2 se = rowse[n];
    int s = se.x, e = se.y;
    for (int i = s; i < e; i += 32) {
        int   srcj[8];
        float wj[8];
        #pragma unroll
        for (int j = 0; j < 8; j++) {
            int t = i + 4 * j + p;
            int ic = (t < e) ? t : (e - 1);   // loop entry guarantees e > s >= 0
            int2 en = csr[ic];                // 16-lane broadcast per slot
            srcj[j] = en.x;
            wj[j] = (t < e) ? __int_as_float(en.y) : 0.0f;
        }
        unsigned int u[8];
        #pragma unroll
        for (int j = 0; j < 8; j++)
            u[j] = hin4[(size_t)srcj[j] * 16 + q];
        #pragma unroll
        for (int j = 0; j < 8; j++) {
            v2f lo = __builtin_amdgcn_cvt_pk_f32_fp8((int)u[j], false);
            v2f hi = __builtin_amdgcn_cvt_pk_f32_fp8((int)u[j], true);
            a0 = fmaf(wj[j], lo.x, a0);
            a1 = fmaf(wj[j], lo.y, a1);
            a2 = fmaf(wj[j], hi.x, a2);
            a3 = fmaf(wj[j], hi.y, a3);
        }
    }
    a0 += __shfl_xor(a0, 16); a0 += __shfl_xor(a0, 32);
    a1 += __shfl_xor(a1, 16); a1 += __shfl_xor(a1, 32);
    a2 += __shfl_xor(a2, 16); a2 += __shfl_xor(a2, 32);
    a3 += __shfl_xor(a3, 16); a3 += __shfl_xor(a3, 32);

    float d = dis[n];
    if (p == 0) {
        uint2 g;
        g.x = f2bf(a0 * d) | (f2bf(a1 * d) << 16);
        g.y = f2bf(a2 * d) | (f2bf(a3 * d) << 16);
        *(uint2*)(Gout + (size_t)n * 32 + q * 2) = g;   // coalesced 128 B row
    }
}

// ------- transform: 16-node MFMA GEMM  h' = relu(G·W + b) (* d if scaleOut) -> fp8 -------
// mfma_f32_16x16x32_bf16: A[m=lane&15][k=quad*8+j], B[k=quad*8+j][n=lane&15],
// D col=lane&15, row=quad*4+reg

__global__ __launch_bounds__(256) void transform_kernel(
    const unsigned short* __restrict__ G, const float* __restrict__ W,
    const float* __restrict__ bias, const float* __restrict__ dis,
    unsigned char* __restrict__ hout8, int N, int scaleOut) {
    int lane = threadIdx.x & 63;
    int wv = (blockIdx.x * blockDim.x + threadIdx.x) >> 6;
    int base = wv * 16;
    if (base >= N) return;
    int col = lane & 15, quad = lane >> 4;

    // B fragments (W is 16 KB fp32, L2-resident; cvt once per wave)
    short8 Bf[4][2];
    #pragma unroll
    for (int nt = 0; nt < 4; nt++)
        #pragma unroll
        for (int kt = 0; kt < 2; kt++)
            #pragma unroll
            for (int j = 0; j < 8; j++)
                Bf[nt][kt][j] = (short)f2bf(W[(kt * 32 + quad * 8 + j) * DEMB + nt * 16 + col]);

    float bv[4];
    #pragma unroll
    for (int nt = 0; nt < 4; nt++) bv[nt] = bias[nt * 16 + col];

    int row = base + col; if (row >= N) row = N - 1;
    short8 Af0 = *(const short8*)(G + (size_t)row * DEMB + quad * 8);
    short8 Af1 = *(const short8*)(G + (size_t)row * DEMB + 32 + quad * 8);

    f32x4 acc[4];
    #pragma unroll
    for (int nt = 0; nt < 4; nt++) {
        f32x4 z = {0.0f, 0.0f, 0.0f, 0.0f};
        z = __builtin_amdgcn_mfma_f32_16x16x32_bf16(Af0, Bf[nt][0], z, 0, 0, 0);
        z = __builtin_amdgcn_mfma_f32_16x16x32_bf16(Af1, Bf[nt][1], z, 0, 0, 0);
        acc[nt] = z;
    }

    #pragma unroll
    for (int reg = 0; reg < 4; reg++) {
        int node = base + quad * 4 + reg;
        if (node >= N) continue;
        float d = dis[node];
        float os = scaleOut ? d : 1.0f;
        #pragma unroll
        for (int nt = 0; nt < 4; nt++) {
            float y = fmaxf(acc[nt][reg] + bv[nt], 0.0f) * os;
            int u = __builtin_amdgcn_cvt_pk_fp8_f32(y, y, 0, false);
            hout8[(size_t)node * DEMB + nt * 16 + col] = (unsigned char)(u & 0xff);
        }
    }
}

// ---------------- decoder + softmax + residual ----------------

__global__ __launch_bounds__(256, 4) void decoder_kernel(
    const unsigned char* __restrict__ h8, const float* __restrict__ x,
    const float* __restrict__ dw1, const float* __restrict__ db1,
    const float* __restrict__ dw2, const float* __restrict__ db2,
    float* __restrict__ out, int N) {
    int lane = threadIdx.x & 63;
    int wid = __builtin_amdgcn_readfirstlane((blockIdx.x * blockDim.x + threadIdx.x) >> 6);
    int n0 = wid * 4;
    if (n0 >= N) return;

    float w1col[DEMB];
    #pragma unroll
    for (int k = 0; k < DEMB; k++) w1col[k] = dw1[k * DEMB + lane];
    float db1v = db1[lane];
    float w20 = dw2[lane * 2], w21 = dw2[lane * 2 + 1];
    float db20 = db2[0], db21 = db2[1];

    float xv = 0.0f;
    if (lane < 8 && n0 * 2 + lane < 2 * N) xv = x[n0 * 2 + lane];

    float myout = 0.0f;
    #pragma unroll
    for (int m = 0; m < 4; m++) {
        int node = n0 + m;
        if (node >= N) continue;
        float hv = __builtin_amdgcn_cvt_f32_fp8((int)h8[(size_t)node * 64 + lane], 0);
        float y = db1v;
        #pragma unroll
        for (int k = 0; k < DEMB; k++)
            y = fmaf(rdlane(hv, k), w1col[k], y);
        float d1 = fmaxf(y, 0.0f);
        float p0 = d1 * w20, p1 = d1 * w21;
        #pragma unroll
        for (int off = 32; off > 0; off >>= 1) {
            p0 += __shfl_xor(p0, off);
            p1 += __shfl_xor(p1, off);
        }
        float o0 = p0 + db20, o1 = p1 + db21;
        float mm = fmaxf(o0, o1);
        float e0 = __expf(o0 - mm), e1 = __expf(o1 - mm);
        float inv = 1.0f / (e0 + e1);
        float r0 = e0 * inv + 2.0f * rdlane(xv, 2 * m);   // wc = [2, 0]
        float r1 = e1 * inv;
        if (lane == 2 * m) myout = r0;
        if (lane == 2 * m + 1) myout = r1;
    }
    if (lane < 8 && n0 * 2 + lane < 2 * N)
        out[n0 * 2 + lane] = myout;
}

// ---------------- launch ----------------

extern "C" void kernel_launch(void* const* d_in, const int* in_sizes, int n_in,
                              void* d_out, int out_size, void* d_ws, size_t ws_size,
                              hipStream_t stream) {
    const float* x      = (const float*)d_in[0];
    const int*   ei     = (const int*)d_in[1];
    const float* ew     = (const float*)d_in[2];
    const float* enc_w1 = (const float*)d_in[3];
    const float* enc_b1 = (const float*)d_in[4];
    const float* enc_w2 = (const float*)d_in[5];
    const float* enc_b2 = (const float*)d_in[6];
    const float* gcn_w  = (const float*)d_in[7];
    const float* gcn_b  = (const float*)d_in[8];
    const float* dec_w1 = (const float*)d_in[9];
    const float* dec_b1 = (const float*)d_in[10];
    const float* dec_w2 = (const float*)d_in[11];
    const float* dec_b2 = (const float*)d_in[12];
    float* out = (float*)d_out;

    const int N = in_sizes[0] / 2;
    const int E = in_sizes[2];
    const int L = in_sizes[7] / (DEMB * DEMB);
    const int NBKT = (N + NPBKT - 1) / NPBKT;

    // workspace layout (256B aligned); h rows 64 B fp8; G (bf16) aliases cells
    char* ws = (char*)d_ws;
    size_t o = 0;
    auto alignup = [](size_t v) { return (v + 255) & ~(size_t)255; };
    unsigned int* hA = (unsigned int*)(ws + o); o = alignup(o + (size_t)N * DEMB);
    unsigned int* hB = (unsigned int*)(ws + o); o = alignup(o + (size_t)N * DEMB);
    float* dis     = (float*)(ws + o); o = alignup(o + (size_t)N * 4);
    int2*  rowse   = (int2*)(ws + o);  o = alignup(o + (size_t)N * 8);
    int*   bktcnt  = (int*)(ws + o);   o = alignup(o + (size_t)1024 * 4);
    int*   bktbase = (int*)(ws + o);   o = alignup(o + (size_t)1025 * 4);
    int*   bktfill = (int*)(ws + o);   o = alignup(o + (size_t)1024 * 4);
    size_t cells_bytes = (size_t)E * 8, g_bytes = (size_t)N * 128;
    size_t un = cells_bytes > g_bytes ? cells_bytes : g_bytes;
    int2*  cells   = (int2*)(ws + o);
    unsigned int* Gbuf = (unsigned int*)(ws + o); o = alignup(o + un);
    int2*  csr     = (int2*)(ws + o);  o = alignup(o + (size_t)E * 8);

    const int TB = 256;
    dim3 blk(TB);
    int NWGA = (E + CHUNK_A - 1) / CHUNK_A;
    dim3 gWave1((N * 64 + TB - 1) / TB);          // wave per node
    dim3 gWave4((N * 16 + TB - 1) / TB);          // wave per 4 nodes
    int tiles = (N + 15) / 16;
    dim3 gTile((tiles + 3) / 4);                  // 4 waves (tiles) per block

    init_bkt_kernel<<<4, blk, 0, stream>>>(bktcnt);
    histA_kernel<<<NWGA, blk, 0, stream>>>(ei, bktcnt, E, NBKT);
    scanB_kernel<<<1, 1024, 0, stream>>>(bktcnt, bktbase, bktfill, NBKT);
    binA_kernel<<<NWGA, blk, 0, stream>>>(ei, ew, bktfill, cells, E, NBKT);
    bucketB_kernel<<<NBKT, blk, 0, stream>>>(cells, bktbase, csr, rowse, dis, N);

    encoder_kernel<<<gWave4, blk, 0, stream>>>(x, dis, enc_w1, enc_b1, enc_w2, enc_b2, hA, N);

    unsigned int* hin = hA;
    unsigned int* hout = hB;
    for (int l = 0; l < L; l++) {
        agg_kernel<<<gWave1, blk, 0, stream>>>(hin, csr, rowse, dis, Gbuf, N);
        transform_kernel<<<gTile, blk, 0, stream>>>((const unsigned short*)Gbuf,
                                                    gcn_w + (size_t)l * DEMB * DEMB,
                                                    gcn_b + (size_t)l * DEMB, dis,
                                                    (unsigned char*)hout, N,
                                                    (l < L - 1) ? 1 : 0);
        unsigned int* t = hin; hin = hout; hout = t;
    }

    decoder_kernel<<<gWave4, blk, 0, stream>>>((const unsigned char*)hin, x,
                                               dec_w1, dec_b1, dec_w2, dec_b2, out, N);
}

// Round 10
// 388.648 us; speedup vs baseline: 1.8393x; 1.0302x over previous
//
#include <hip/hip_runtime.h>
#include <hip/hip_bf16.h>
#include <math.h>

#define DEMB 64
#define NPBKT 256          // nodes per coarse bucket (c >> 8)
#define CAPB 8192          // fixed capacity per bucket region (expected 4096)
#define CHUNK_S 2048       // edges per binS workgroup
#define SENT_CAP 5632      // LDS staging entries in pass B (45 KB)

typedef float v2f __attribute__((ext_vector_type(2)));
typedef short short8 __attribute__((ext_vector_type(8)));
typedef float f32x4 __attribute__((ext_vector_type(4)));

// ---------------- helpers ----------------

__device__ __forceinline__ float rdlane(float v, int k) {
    return __int_as_float(__builtin_amdgcn_readlane(__float_as_int(v), k));
}
__device__ __forceinline__ unsigned int f2bf(float f) {
    union { float f; unsigned int i; } c; c.f = f;
    unsigned int r = c.i + 0x7FFFu + ((c.i >> 16) & 1u);   // RNE
    return r >> 16;
}

// pack 64 lanes' y (feature=lane) into fp8 row; lanes 0..15 store one dword each
__device__ __forceinline__ void pack_store_fp8(float y, unsigned int* __restrict__ dst, int lane) {
    float y0 = __shfl(y, 4 * lane + 0);
    float y1 = __shfl(y, 4 * lane + 1);
    float y2 = __shfl(y, 4 * lane + 2);
    float y3 = __shfl(y, 4 * lane + 3);
    int u = __builtin_amdgcn_cvt_pk_fp8_f32(y0, y1, 0, false);
    u = __builtin_amdgcn_cvt_pk_fp8_f32(y2, y3, u, true);
    if (lane < 16) dst[lane] = (unsigned int)u;
}

// ---------------- preprocessing: single-pass fixed-cap counting sort ----------------
// bktctl[0..511] = per-bucket fill; bktctl[512] = overflow count; bktctl[513] = tail fill

__global__ void initS_kernel(int* __restrict__ bktctl) {
    int i = blockIdx.x * blockDim.x + threadIdx.x;
    if (i < 514) bktctl[i] = 0;
}

// one pass: LDS histogram of this chunk, reserve per-bucket runs, scatter entries.
// entry: x = (c&255)<<20 | r, y = bits(ew). Overflow -> ovf (int4: c, r, ewbits, 0)
__global__ __launch_bounds__(256) void binS_kernel(const int* __restrict__ ei,
                                                   const float* __restrict__ ew,
                                                   int* __restrict__ bktctl,
                                                   int2* __restrict__ cells,
                                                   int4* __restrict__ ovf,
                                                   int E, int NBKT) {
    __shared__ int lh[512];
    __shared__ int lbase[512];
    __shared__ int lcur[512];
    int t = threadIdx.x;
    for (int b = t; b < NBKT; b += 256) { lh[b] = 0; lcur[b] = 0; }
    __syncthreads();
    int base = blockIdx.x * CHUNK_S;
    int end = base + CHUNK_S; if (end > E) end = E;

    int cc[CHUNK_S / 256];
    int nloc = 0;
    for (int i = base + t; i < end; i += 256, nloc++) {
        int c = ei[E + i];
        cc[nloc] = c;
        atomicAdd(&lh[((unsigned int)c) >> 8], 1);
    }
    __syncthreads();
    for (int b = t; b < NBKT; b += 256)
        if (lh[b]) lbase[b] = atomicAdd(&bktctl[b], lh[b]);
    __syncthreads();
    int k = 0;
    for (int i = base + t; i < end; i += 256, k++) {
        unsigned int c = (unsigned int)cc[k];
        unsigned int r = (unsigned int)ei[i];
        int wbits = __float_as_int(ew[i]);
        int bkt = c >> 8;
        int rel = lbase[bkt] + atomicAdd(&lcur[bkt], 1);
        if (rel < CAPB) {
            cells[(size_t)bkt * CAPB + rel] = make_int2((int)(((c & 255u) << 20) | r), wbits);
        } else {
            int op = atomicAdd(&bktctl[512], 1);
            ovf[op] = make_int4((int)c, (int)r, wbits, 0);
        }
    }
}

// pass B: per bucket — count + weighted degree, scan, write dis/rowse,
// sort entries into LDS, stream CSR out coalesced into the bucket's fixed region.
__global__ __launch_bounds__(256) void bucketB_kernel(
    const int2* __restrict__ cells, int* __restrict__ bktctl,
    const int4* __restrict__ ovf,
    int2* __restrict__ csr, int2* __restrict__ rowse, float* __restrict__ dis,
    int N, int NBKT) {
    __shared__ int scnt[NPBKT];
    __shared__ float sdeg[NPBKT];
    __shared__ int sstart[NPBKT];
    __shared__ int sfill[NPBKT];
    __shared__ int ssc[NPBKT];
    __shared__ int sbase;
    __shared__ int2 sout[SENT_CAP];

    int b = blockIdx.x;
    int t = threadIdx.x;
    int nodebase = b << 8;
    int nNodes = N - nodebase; if (nNodes > NPBKT) nNodes = NPBKT;

    if (t < NPBKT) { scnt[t] = 0; sdeg[t] = 1.0f; sfill[t] = 0; }   // self-loop deg=1
    __syncthreads();

    int total = bktctl[b];
    int inreg = total < CAPB ? total : CAPB;
    int oc = bktctl[512];
    const int2* reg = cells + (size_t)b * CAPB;

    for (int i = t; i < inreg; i += 256) {
        int2 en = reg[i];
        unsigned int ld = ((unsigned int)en.x) >> 20;
        atomicAdd(&scnt[ld], 1);
        atomicAdd(&sdeg[ld], __int_as_float(en.y));
    }
    for (int i = t; i < oc; i += 256) {        // oc == 0 in practice
        int4 ov = ovf[i];
        if ((((unsigned int)ov.x) >> 8) == (unsigned int)b) {
            unsigned int ld = ((unsigned int)ov.x) & 255u;
            atomicAdd(&scnt[ld], 1);
            atomicAdd(&sdeg[ld], __int_as_float(ov.z));
        }
    }
    __syncthreads();

    int mine = scnt[t];
    ssc[t] = mine;
    __syncthreads();
    for (int off = 1; off < NPBKT; off <<= 1) {
        int v = (t >= off) ? ssc[t - off] : 0;
        __syncthreads();
        ssc[t] += v;
        __syncthreads();
    }
    sstart[t] = ssc[t] - mine;
    if (t == 0)
        sbase = (total <= CAPB) ? b * CAPB
                                : NBKT * CAPB + atomicAdd(&bktctl[513], total);
    __syncthreads();
    int outbase = sbase;

    if (t < nNodes) {
        int node = nodebase + t;
        dis[node] = rsqrtf(sdeg[t]);
        rowse[node] = make_int2(outbase + sstart[t], outbase + sstart[t] + scnt[t]);
    }

    if (total <= SENT_CAP) {
        for (int i = t; i < inreg; i += 256) {
            int2 en = reg[i];
            unsigned int ux = (unsigned int)en.x;
            unsigned int ld = ux >> 20;
            int pos = sstart[ld] + atomicAdd(&sfill[ld], 1);
            sout[pos] = make_int2((int)(ux & 0xFFFFFu), en.y);
        }
        for (int i = t; i < oc; i += 256) {
            int4 ov = ovf[i];
            if ((((unsigned int)ov.x) >> 8) == (unsigned int)b) {
                unsigned int ld = ((unsigned int)ov.x) & 255u;
                int pos = sstart[ld] + atomicAdd(&sfill[ld], 1);
                sout[pos] = make_int2(ov.y, ov.z);
            }
        }
        __syncthreads();
        for (int i = t; i < total; i += 256)
            csr[outbase + i] = sout[i];
    } else {
        // pathological-skew fallback: direct global scatter
        for (int i = t; i < inreg; i += 256) {
            int2 en = reg[i];
            unsigned int ux = (unsigned int)en.x;
            unsigned int ld = ux >> 20;
            int pos = atomicAdd(&sfill[ld], 1);
            csr[outbase + sstart[ld] + pos] = make_int2((int)(ux & 0xFFFFFu), en.y);
        }
        for (int i = t; i < oc; i += 256) {
            int4 ov = ovf[i];
            if ((((unsigned int)ov.x) >> 8) == (unsigned int)b) {
                unsigned int ld = ((unsigned int)ov.x) & 255u;
                int pos = atomicAdd(&sfill[ld], 1);
                csr[outbase + sstart[ld] + pos] = make_int2(ov.y, ov.z);
            }
        }
    }
}

// ---------------- encoder: stores s = dis * h_enc as fp8 ----------------

__global__ __launch_bounds__(256, 4) void encoder_kernel(
    const float* __restrict__ x, const float* __restrict__ dis,
    const float* __restrict__ w1, const float* __restrict__ b1,
    const float* __restrict__ w2, const float* __restrict__ b2,
    unsigned int* __restrict__ hout4, int N) {
    int lane = threadIdx.x & 63;
    int wid = __builtin_amdgcn_readfirstlane((blockIdx.x * blockDim.x + threadIdx.x) >> 6);
    int n0 = wid * 4;
    if (n0 >= N) return;

    float w2col[DEMB];
    #pragma unroll
    for (int k = 0; k < DEMB; k++) w2col[k] = w2[k * DEMB + lane];
    float w1a = w1[lane], w1b = w1[DEMB + lane];
    float b1v = b1[lane], b2v = b2[lane];

    float xv = 0.0f;
    if (lane < 8 && n0 * 2 + lane < 2 * N) xv = x[n0 * 2 + lane];

    #pragma unroll
    for (int m = 0; m < 4; m++) {
        int node = n0 + m;
        if (node >= N) continue;
        float x0 = rdlane(xv, 2 * m);
        float x1 = rdlane(xv, 2 * m + 1);
        float t = fmaxf(0.0f, fmaf(x0, w1a, fmaf(x1, w1b, b1v)));
        float y = b2v;
        #pragma unroll
        for (int k = 0; k < DEMB; k++)
            y = fmaf(rdlane(t, k), w2col[k], y);
        pack_store_fp8(y * dis[node], hout4 + (size_t)node * 16, lane);
    }
}

// ------- aggregation: wave per node, quad gathers on fp8 rows, early-exit halves -------
// writes g = dis_c * (Σ ew*s_src + s_c) as bf16 row [64] (128 B)

__global__ __launch_bounds__(256, 6) void agg_kernel(
    const unsigned int* __restrict__ hin4, const int2* __restrict__ csr,
    const int2* __restrict__ rowse, const float* __restrict__ dis,
    unsigned int* __restrict__ Gout, int N) {
    int lane = threadIdx.x & 63;
    int n = __builtin_amdgcn_readfirstlane((blockIdx.x * blockDim.x + threadIdx.x) >> 6);
    if (n >= N) return;

    int p = lane >> 4;        // edge slot (0..3), interleaved stride-4
    int q = lane & 15;        // feature quad (features 4q..4q+3)

    unsigned int su = hin4[(size_t)n * 16 + q];
    float sw = (p == 0) ? 1.0f : 0.0f;
    v2f slo = __builtin_amdgcn_cvt_pk_f32_fp8((int)su, false);
    v2f shi = __builtin_amdgcn_cvt_pk_f32_fp8((int)su, true);
    float a0 = slo.x * sw, a1 = slo.y * sw, a2 = shi.x * sw, a3 = shi.y * sw;

    int2 se = rowse[n];
    int s = se.x, e = se.y;
    for (int i = s; i < e; i += 32) {
        // half 1: edges i .. i+15
        {
            int   srcj[4];
            float wj[4];
            #pragma unroll
            for (int j = 0; j < 4; j++) {
                int t = i + 4 * j + p;
                int ic = (t < e) ? t : (e - 1);
                int2 en = csr[ic];
                srcj[j] = en.x;
                wj[j] = (t < e) ? __int_as_float(en.y) : 0.0f;
            }
            unsigned int u[4];
            #pragma unroll
            for (int j = 0; j < 4; j++)
                u[j] = hin4[(size_t)srcj[j] * 16 + q];
            #pragma unroll
            for (int j = 0; j < 4; j++) {
                v2f lo = __builtin_amdgcn_cvt_pk_f32_fp8((int)u[j], false);
                v2f hi = __builtin_amdgcn_cvt_pk_f32_fp8((int)u[j], true);
                a0 = fmaf(wj[j], lo.x, a0);
                a1 = fmaf(wj[j], lo.y, a1);
                a2 = fmaf(wj[j], hi.x, a2);
                a3 = fmaf(wj[j], hi.y, a3);
            }
        }
        // half 2: edges i+16 .. i+31 (wave-uniform skip for short rows)
        if (i + 16 < e) {
            int   srcj[4];
            float wj[4];
            #pragma unroll
            for (int j = 0; j < 4; j++) {
                int t = i + 16 + 4 * j + p;
                int ic = (t < e) ? t : (e - 1);
                int2 en = csr[ic];
                srcj[j] = en.x;
                wj[j] = (t < e) ? __int_as_float(en.y) : 0.0f;
            }
            unsigned int u[4];
            #pragma unroll
            for (int j = 0; j < 4; j++)
                u[j] = hin4[(size_t)srcj[j] * 16 + q];
            #pragma unroll
            for (int j = 0; j < 4; j++) {
                v2f lo = __builtin_amdgcn_cvt_pk_f32_fp8((int)u[j], false);
                v2f hi = __builtin_amdgcn_cvt_pk_f32_fp8((int)u[j], true);
                a0 = fmaf(wj[j], lo.x, a0);
                a1 = fmaf(wj[j], lo.y, a1);
                a2 = fmaf(wj[j], hi.x, a2);
                a3 = fmaf(wj[j], hi.y, a3);
            }
        }
    }
    a0 += __shfl_xor(a0, 16); a0 += __shfl_xor(a0, 32);
    a1 += __shfl_xor(a1, 16); a1 += __shfl_xor(a1, 32);
    a2 += __shfl_xor(a2, 16); a2 += __shfl_xor(a2, 32);
    a3 += __shfl_xor(a3, 16); a3 += __shfl_xor(a3, 32);

    float d = dis[n];
    if (p == 0) {
        uint2 g;
        g.x = f2bf(a0 * d) | (f2bf(a1 * d) << 16);
        g.y = f2bf(a2 * d) | (f2bf(a3 * d) << 16);
        *(uint2*)(Gout + (size_t)n * 32 + q * 2) = g;   // coalesced 128 B row
    }
}

// ------- transform: 16-node MFMA GEMM  h' = relu(G·W + b) (* d if scaleOut) -> fp8 -------

__global__ __launch_bounds__(256) void transform_kernel(
    const unsigned short* __restrict__ G, const float* __restrict__ W,
    const float* __restrict__ bias, const float* __restrict__ dis,
    unsigned char* __restrict__ hout8, int N, int scaleOut) {
    int lane = threadIdx.x & 63;
    int wv = (blockIdx.x * blockDim.x + threadIdx.x) >> 6;
    int base = wv * 16;
    if (base >= N) return;
    int col = lane & 15, quad = lane >> 4;

    short8 Bf[4][2];
    #pragma unroll
    for (int nt = 0; nt < 4; nt++)
        #pragma unroll
        for (int kt = 0; kt < 2; kt++)
            #pragma unroll
            for (int j = 0; j < 8; j++)
                Bf[nt][kt][j] = (short)f2bf(W[(kt * 32 + quad * 8 + j) * DEMB + nt * 16 + col]);

    float bv[4];
    #pragma unroll
    for (int nt = 0; nt < 4; nt++) bv[nt] = bias[nt * 16 + col];

    int row = base + col; if (row >= N) row = N - 1;
    short8 Af0 = *(const short8*)(G + (size_t)row * DEMB + quad * 8);
    short8 Af1 = *(const short8*)(G + (size_t)row * DEMB + 32 + quad * 8);

    f32x4 acc[4];
    #pragma unroll
    for (int nt = 0; nt < 4; nt++) {
        f32x4 z = {0.0f, 0.0f, 0.0f, 0.0f};
        z = __builtin_amdgcn_mfma_f32_16x16x32_bf16(Af0, Bf[nt][0], z, 0, 0, 0);
        z = __builtin_amdgcn_mfma_f32_16x16x32_bf16(Af1, Bf[nt][1], z, 0, 0, 0);
        acc[nt] = z;
    }

    #pragma unroll
    for (int reg = 0; reg < 4; reg++) {
        int node = base + quad * 4 + reg;
        if (node >= N) continue;
        float d = dis[node];
        float os = scaleOut ? d : 1.0f;
        #pragma unroll
        for (int nt = 0; nt < 4; nt++) {
            float y = fmaxf(acc[nt][reg] + bv[nt], 0.0f) * os;
            int u = __builtin_amdgcn_cvt_pk_fp8_f32(y, y, 0, false);
            hout8[(size_t)node * DEMB + nt * 16 + col] = (unsigned char)(u & 0xff);
        }
    }
}

// ---------------- decoder + softmax + residual ----------------

__global__ __launch_bounds__(256, 4) void decoder_kernel(
    const unsigned char* __restrict__ h8, const float* __restrict__ x,
    const float* __restrict__ dw1, const float* __restrict__ db1,
    const float* __restrict__ dw2, const float* __restrict__ db2,
    float* __restrict__ out, int N) {
    int lane = threadIdx.x & 63;
    int wid = __builtin_amdgcn_readfirstlane((blockIdx.x * blockDim.x + threadIdx.x) >> 6);
    int n0 = wid * 4;
    if (n0 >= N) return;

    float w1col[DEMB];
    #pragma unroll
    for (int k = 0; k < DEMB; k++) w1col[k] = dw1[k * DEMB + lane];
    float db1v = db1[lane];
    float w20 = dw2[lane * 2], w21 = dw2[lane * 2 + 1];
    float db20 = db2[0], db21 = db2[1];

    float xv = 0.0f;
    if (lane < 8 && n0 * 2 + lane < 2 * N) xv = x[n0 * 2 + lane];

    float myout = 0.0f;
    #pragma unroll
    for (int m = 0; m < 4; m++) {
        int node = n0 + m;
        if (node >= N) continue;
        float hv = __builtin_amdgcn_cvt_f32_fp8((int)h8[(size_t)node * 64 + lane], 0);
        float y = db1v;
        #pragma unroll
        for (int k = 0; k < DEMB; k++)
            y = fmaf(rdlane(hv, k), w1col[k], y);
        float d1 = fmaxf(y, 0.0f);
        float p0 = d1 * w20, p1 = d1 * w21;
        #pragma unroll
        for (int off = 32; off > 0; off >>= 1) {
            p0 += __shfl_xor(p0, off);
            p1 += __shfl_xor(p1, off);
        }
        float o0 = p0 + db20, o1 = p1 + db21;
        float mm = fmaxf(o0, o1);
        float e0 = __expf(o0 - mm), e1 = __expf(o1 - mm);
        float inv = 1.0f / (e0 + e1);
        float r0 = e0 * inv + 2.0f * rdlane(xv, 2 * m);   // wc = [2, 0]
        float r1 = e1 * inv;
        if (lane == 2 * m) myout = r0;
        if (lane == 2 * m + 1) myout = r1;
    }
    if (lane < 8 && n0 * 2 + lane < 2 * N)
        out[n0 * 2 + lane] = myout;
}

// ---------------- launch ----------------

extern "C" void kernel_launch(void* const* d_in, const int* in_sizes, int n_in,
                              void* d_out, int out_size, void* d_ws, size_t ws_size,
                              hipStream_t stream) {
    const float* x      = (const float*)d_in[0];
    const int*   ei     = (const int*)d_in[1];
    const float* ew     = (const float*)d_in[2];
    const float* enc_w1 = (const float*)d_in[3];
    const float* enc_b1 = (const float*)d_in[4];
    const float* enc_w2 = (const float*)d_in[5];
    const float* enc_b2 = (const float*)d_in[6];
    const float* gcn_w  = (const float*)d_in[7];
    const float* gcn_b  = (const float*)d_in[8];
    const float* dec_w1 = (const float*)d_in[9];
    const float* dec_b1 = (const float*)d_in[10];
    const float* dec_w2 = (const float*)d_in[11];
    const float* dec_b2 = (const float*)d_in[12];
    float* out = (float*)d_out;

    const int N = in_sizes[0] / 2;
    const int E = in_sizes[2];
    const int L = in_sizes[7] / (DEMB * DEMB);
    const int NBKT = (N + NPBKT - 1) / NPBKT;

    // workspace layout (256B aligned); h rows 64 B fp8; G (bf16) aliases cells
    char* ws = (char*)d_ws;
    size_t o = 0;
    auto alignup = [](size_t v) { return (v + 255) & ~(size_t)255; };
    unsigned int* hA = (unsigned int*)(ws + o); o = alignup(o + (size_t)N * DEMB);
    unsigned int* hB = (unsigned int*)(ws + o); o = alignup(o + (size_t)N * DEMB);
    float* dis     = (float*)(ws + o); o = alignup(o + (size_t)N * 4);
    int2*  rowse   = (int2*)(ws + o);  o = alignup(o + (size_t)N * 8);
    int*   bktctl  = (int*)(ws + o);   o = alignup(o + (size_t)520 * 4);
    size_t cells_bytes = (size_t)NBKT * CAPB * 8, g_bytes = (size_t)N * 128;
    size_t un = cells_bytes > g_bytes ? cells_bytes : g_bytes;
    int2*  cells   = (int2*)(ws + o);
    unsigned int* Gbuf = (unsigned int*)(ws + o); o = alignup(o + un);
    int2*  csr     = (int2*)(ws + o);  o = alignup(o + ((size_t)NBKT * CAPB + (size_t)E) * 8);
    int4*  ovf     = (int4*)(ws + o);  o = alignup(o + (size_t)E * 16);

    const int TB = 256;
    dim3 blk(TB);
    int NWGS = (E + CHUNK_S - 1) / CHUNK_S;
    dim3 gWave1((N * 64 + TB - 1) / TB);          // wave per node
    dim3 gWave4((N * 16 + TB - 1) / TB);          // wave per 4 nodes
    int tiles = (N + 15) / 16;
    dim3 gTile((tiles + 3) / 4);                  // 4 waves (tiles) per block

    initS_kernel<<<3, blk, 0, stream>>>(bktctl);
    binS_kernel<<<NWGS, blk, 0, stream>>>(ei, ew, bktctl, cells, ovf, E, NBKT);
    bucketB_kernel<<<NBKT, blk, 0, stream>>>(cells, bktctl, ovf, csr, rowse, dis, N, NBKT);

    encoder_kernel<<<gWave4, blk, 0, stream>>>(x, dis, enc_w1, enc_b1, enc_w2, enc_b2, hA, N);

    unsigned int* hin = hA;
    unsigned int* hout = hB;
    for (int l = 0; l < L; l++) {
        agg_kernel<<<gWave1, blk, 0, stream>>>(hin, csr, rowse, dis, Gbuf, N);
        transform_kernel<<<gTile, blk, 0, stream>>>((const unsigned short*)Gbuf,
                                                    gcn_w + (size_t)l * DEMB * DEMB,
                                                    gcn_b + (size_t)l * DEMB, dis,
                                                    (unsigned char*)hout, N,
                                                    (l < L - 1) ? 1 : 0);
        unsigned int* t = hin; hin = hout; hout = t;
    }

    decoder_kernel<<<gWave4, blk, 0, stream>>>((const unsigned char*)hin, x,
                                               dec_w1, dec_b1, dec_w2, dec_b2, out, N);
}